// Round 10
// baseline (419.243 us; speedup 1.0000x reference)
//
#include <hip/hip_runtime.h>
#include <stdint.h>

typedef __attribute__((ext_vector_type(8))) short short8;
typedef __attribute__((ext_vector_type(4))) float f32x4;
typedef __attribute__((ext_vector_type(2))) float f32x2;

#define NN 1024
#define NBATCH 16384

__device__ __forceinline__ unsigned short f32_to_bf16_rne(float f) {
  unsigned int u = __float_as_uint(f);
  unsigned int r = (u + 0x7fffu + ((u >> 16) & 1u)) >> 16;
  return (unsigned short)r;
}

__device__ __forceinline__ unsigned int pack2bf(float lo, float hi) {
  return (unsigned int)f32_to_bf16_rne(lo) | ((unsigned int)f32_to_bf16_rne(hi) << 16);
}

// acc = a*b + acc, forced VOP3P (R9 evidence: compiler scalarizes f32x2 math).
__device__ __forceinline__ void pkfma(f32x2& acc, f32x2 a, f32x2 b) {
  asm("v_pk_fma_f32 %0, %1, %2, %0" : "+v"(acc) : "v"(a), "v"(b));
}

// 64-lane all-reduce sum: 4 DPP stages + permlane16/32_swap (all VALU).
__device__ __forceinline__ float allsum64(float x) {
  x += __int_as_float(__builtin_amdgcn_update_dpp(0, __float_as_int(x), 0xB1, 0xF, 0xF, true));   // xor1
  x += __int_as_float(__builtin_amdgcn_update_dpp(0, __float_as_int(x), 0x4E, 0xF, 0xF, true));   // xor2
  x += __int_as_float(__builtin_amdgcn_update_dpp(0, __float_as_int(x), 0x141, 0xF, 0xF, true));  // xor4
  x += __int_as_float(__builtin_amdgcn_update_dpp(0, __float_as_int(x), 0x140, 0xF, 0xF, true));  // xor8
#if __has_builtin(__builtin_amdgcn_permlane16_swap) && __has_builtin(__builtin_amdgcn_permlane32_swap)
  {
    auto r16 = __builtin_amdgcn_permlane16_swap(__float_as_uint(x), __float_as_uint(x), false, false);
    x = __uint_as_float(r16[0]) + __uint_as_float(r16[1]);
    auto r32 = __builtin_amdgcn_permlane32_swap(__float_as_uint(x), __float_as_uint(x), false, false);
    x = __uint_as_float(r32[0]) + __uint_as_float(r32[1]);
  }
#else
  x += __int_as_float(__builtin_amdgcn_ds_swizzle(__float_as_int(x), 0x401F));
  x += __shfl_xor(x, 32);
#endif
  return x;
}

// -------------------- prep: tau = 2/(u.u), sigmas --------------------
__global__ __launch_bounds__(256) void prep_kernel(
    const float* __restrict__ U, const float* __restrict__ V,
    const float* __restrict__ p, float* __restrict__ tau_u,
    float* __restrict__ tau_v, float* __restrict__ sigmas) {
  int wave = threadIdx.x >> 6, lane = threadIdx.x & 63;
  int row = blockIdx.x * 4 + wave;
  if (row < 2048) {
    const float* u = (row < NN) ? (U + (size_t)row * NN) : (V + (size_t)(row - NN) * NN);
    float s = 0.f;
#pragma unroll
    for (int t = 0; t < 16; ++t) { float a = u[lane + (t << 6)]; s += a * a; }
    s = allsum64(s);
    if (lane == 0) {
      float tau = 2.0f / s;
      if (row < NN) tau_u[row] = tau;
      else tau_v[row - NN] = tau;
    }
  } else if (row < 2064) {
    int j = ((row - 2048) << 6) + lane;
    float pj = p[j];
    float sg = 1.0f / (1.0f + expf(-pj));
    sigmas[j] = 0.9f * (sg - 0.5f) + 0.55f;  // r=0.45, mean=0.55
  }
}

// -------------------- gram + T8 per block of 8 reflectors --------------------
__global__ __launch_bounds__(64) void gram_t8_kernel(
    const float* __restrict__ U, const float* __restrict__ V,
    const float* __restrict__ tau_u, const float* __restrict__ tau_v,
    float* __restrict__ T8all) {
  __shared__ float G[64];
  const int blk = blockIdx.x;
  const int lane = threadIdx.x;
  const float* bank;
  int rbase, rsign, st;
  if (blk < 128) { bank = U; rbase = 8 * blk; rsign = 1; st = 8 * blk; }
  else { int s = blk - 128; bank = V; rbase = 1023 - 8 * s; rsign = -1; st = 1016 - 8 * s; }

  if (lane < 28) {
    int j = 1, k = 0, t = lane;
    for (int jj = 1; jj < 8; ++jj) {
      int lo = jj * (jj - 1) / 2, hi = jj * (jj + 1) / 2;
      if (t >= lo && t < hi) { j = jj; k = t - lo; }
    }
    const float* rk = bank + (size_t)(rbase + rsign * k) * NN;
    const float* rj = bank + (size_t)(rbase + rsign * j) * NN;
    float acc = 0.f;
    for (int i = st >> 2; i < 256; ++i) {
      float4 a = *reinterpret_cast<const float4*>(rk + 4 * i);
      float4 b = *reinterpret_cast<const float4*>(rj + 4 * i);
      acc += a.x * b.x + a.y * b.y + a.z * b.z + a.w * b.w;
    }
    G[k * 8 + j] = acc;
  }
  __syncthreads();

  if (lane < 8) {
    float Tr[8];
#pragma unroll
    for (int j = 0; j < 8; ++j) Tr[j] = 0.f;
#pragma unroll
    for (int j = 0; j < 8; ++j) {
      int grow = rbase + rsign * j;
      float tj = (blk < 128) ? tau_u[grow] : tau_v[grow];
      float a = 0.f;
#pragma unroll
      for (int k = 0; k < 8; ++k) {
        if (k < j) a += Tr[k] * G[k * 8 + j];
      }
      Tr[j] = (lane == j) ? tj : (-tj * a);
    }
#pragma unroll
    for (int j = 0; j < 8; ++j) T8all[(size_t)blk * 64 + lane * 8 + j] = Tr[j];
  }
}

// -------------------- build 16 eighth-chains: 1024 blocks x 256 thr, 4 rows/wave ----
// c=0..7:  U side, A_{c+1} = H_u(128c)..H_u(128c+127) ascending.  Q0 = c>>1.
// c=8..15: V side, B_{8-cc} (cc=c-8) = H_v(1023-128cc)..H_v(896-128cc) descending.
//          Q0 = (7-cc)>>1.
// Natural CU balance: resident quartet {g, g+4, g+8, g+12} always sums to 10
// quarter-units (blocks i, i+256, i+512, i+768 co-resident under round-robin).
// SINGLE-buffered LDS (33 KB) -> 4 blocks/CU (vs 2 at 66 KB): fills the 58%
// stall fraction R9's PMC exposed. Two barriers per step.
// Store: even c row-major, odd c transposed (feeds the pairwise compose tree).
__device__ __forceinline__ void stage16(int c, int s, float* lbuf, float* tbuf,
    const float* __restrict__ U, const float* __restrict__ V,
    const float* __restrict__ T8all, int wave, int lane, int q0) {
  int rbase, rsign, t8i;
  const float* bank;
  if (c < 8) { bank = U; rbase = 128 * c + 8 * s; rsign = 1; t8i = 16 * c + s; }
  else { int cc = c - 8; bank = V; rbase = 1023 - 128 * cc - 8 * s; rsign = -1; t8i = 128 + 16 * cc + s; }
#pragma unroll
  for (int k = 0; k < 8; ++k) {
    const int chunk = (wave << 3) + k;  // 4 waves x 8 chunks = 8 slots x 4 quarters
    const int slot = chunk >> 2, q = chunk & 3;
    if (q < q0) continue;
    const int grow = rbase + rsign * slot;
    const float* gsrc = bank + (size_t)grow * NN + q * 256 + lane * 4;
    float* ldst = lbuf + slot * NN + q * 256;
    __builtin_amdgcn_global_load_lds(
        (const __attribute__((address_space(1))) void*)gsrc,
        (__attribute__((address_space(3))) void*)ldst, 16, 0, 0);
  }
  if (wave == 0 && lane < 16) {
    float4 t = *reinterpret_cast<const float4*>(T8all + (size_t)t8i * 64 + lane * 4);
    *reinterpret_cast<float4*>(tbuf + lane * 4) = t;
  }
}

// Two-pass WY-8 on FOUR rows per wave, forced v_pk_fma_f32.
template <int Q0>
__device__ __forceinline__ void apply_block4(const float* __restrict__ ub,
    const float* __restrict__ tb, f32x2 v[4][8], int lane) {
  float c[4][8];
  // pass 1: dots
#pragma unroll
  for (int j = 0; j < 8; ++j) {
    f32x2 a0 = {0.f, 0.f}, a1 = {0.f, 0.f}, a2 = {0.f, 0.f}, a3 = {0.f, 0.f};
#pragma unroll
    for (int q = Q0; q < 4; ++q) {
      const float4 uu = *reinterpret_cast<const float4*>(&ub[j * NN + q * 256 + lane * 4]);
      const f32x2 u0 = {uu.x, uu.y}, u1 = {uu.z, uu.w};
      pkfma(a0, u0, v[0][2 * q]); pkfma(a0, u1, v[0][2 * q + 1]);
      pkfma(a1, u0, v[1][2 * q]); pkfma(a1, u1, v[1][2 * q + 1]);
      pkfma(a2, u0, v[2][2 * q]); pkfma(a2, u1, v[2][2 * q + 1]);
      pkfma(a3, u0, v[3][2 * q]); pkfma(a3, u1, v[3][2 * q + 1]);
    }
    c[0][j] = a0[0] + a0[1]; c[1][j] = a1[0] + a1[1];
    c[2][j] = a2[0] + a2[1]; c[3][j] = a3[0] + a3[1];
  }
#pragma unroll
  for (int r = 0; r < 4; ++r)
#pragma unroll
    for (int j = 0; j < 8; ++j) c[r][j] = allsum64(c[r][j]);
  // c <- -(c*T) in place, descending j (k<j entries still original).
#pragma unroll
  for (int j = 7; j >= 0; --j) {
#pragma unroll
    for (int r = 0; r < 4; ++r) {
      float acc = 0.f;
#pragma unroll
      for (int k = 0; k < 8; ++k) {
        if (k <= j) acc -= c[r][k] * tb[k * 8 + j];
      }
      c[r][j] = acc;  // = -w  -> pass 2 is pure pk-fma
    }
  }
  // pass 2: v += (-w)*u
#pragma unroll
  for (int q = Q0; q < 4; ++q) {
#pragma unroll
    for (int j = 0; j < 8; ++j) {
      const float4 uu = *reinterpret_cast<const float4*>(&ub[j * NN + q * 256 + lane * 4]);
      const f32x2 u0 = {uu.x, uu.y}, u1 = {uu.z, uu.w};
#pragma unroll
      for (int r = 0; r < 4; ++r) {
        const f32x2 wp = {c[r][j], c[r][j]};
        pkfma(v[r][2 * q], wp, u0);
        pkfma(v[r][2 * q + 1], wp, u1);
      }
    }
  }
}

__global__ __launch_bounds__(256) void build16_kernel(
    const float* __restrict__ U, const float* __restrict__ V,
    const float* __restrict__ T8all, unsigned short* __restrict__ chains) {
  __shared__ float ubuf[8 * NN];   // 32 KB, single-buffered
  __shared__ float tbuf[64];
  const int tid = threadIdx.x;
  const int wave = tid >> 6, lane = tid & 63;
  const int c = blockIdx.x >> 6;  // 16 chains x 64 blocks
  const int q0c = (c < 8) ? (c >> 1) : ((15 - c) >> 1);
  const int row0 = ((blockIdx.x & 63) << 4) + (wave << 2);

  f32x2 v[4][8];
#pragma unroll
  for (int q = 0; q < 4; ++q)
#pragma unroll
    for (int e = 0; e < 4; ++e) {
      const int el = 256 * q + 4 * lane + e;
#pragma unroll
      for (int r = 0; r < 4; ++r)
        v[r][2 * q + (e >> 1)][e & 1] = (el == row0 + r) ? 1.0f : 0.0f;
    }

#define CHAIN_LOOP(Q0C)                                               \
  for (int s = 0; s < 16; ++s) {                                      \
    stage16(c, s, ubuf, tbuf, U, V, T8all, wave, lane, Q0C);          \
    __syncthreads(); /* vmcnt+lgkm drained: ubuf/tbuf ready */        \
    apply_block4<Q0C>(ubuf, tbuf, v, lane);                           \
    __syncthreads(); /* all reads done before next overwrite */      \
  }
  switch (q0c) {
    case 0: CHAIN_LOOP(0) break;
    case 1: CHAIN_LOOP(1) break;
    case 2: CHAIN_LOOP(2) break;
    default: CHAIN_LOOP(3) break;
  }
#undef CHAIN_LOOP

  unsigned short* dst = chains + (size_t)c * NN * NN;
  if ((c & 1) == 0) {  // row-major
#pragma unroll
    for (int r = 0; r < 4; ++r) {
#pragma unroll
      for (int q = 0; q < 4; ++q) {
        ushort4 pk;
        pk.x = f32_to_bf16_rne(v[r][2 * q][0]);
        pk.y = f32_to_bf16_rne(v[r][2 * q][1]);
        pk.z = f32_to_bf16_rne(v[r][2 * q + 1][0]);
        pk.w = f32_to_bf16_rne(v[r][2 * q + 1][1]);
        *reinterpret_cast<ushort4*>(&dst[(size_t)(row0 + r) * NN + 256 * q + 4 * lane]) = pk;
      }
    }
  } else {  // transposed: dst[e][row] = chain[row][e]
#pragma unroll
    for (int q = 0; q < 4; ++q)
#pragma unroll
      for (int e = 0; e < 4; ++e) {
        const size_t el = 256 * q + 4 * lane + e;
        ushort4 pk;
        pk.x = f32_to_bf16_rne(v[0][2 * q + (e >> 1)][e & 1]);
        pk.y = f32_to_bf16_rne(v[1][2 * q + (e >> 1)][e & 1]);
        pk.z = f32_to_bf16_rne(v[2][2 * q + (e >> 1)][e & 1]);
        pk.w = f32_to_bf16_rne(v[3][2 * q + (e >> 1)][e & 1]);
        *reinterpret_cast<ushort4*>(&dst[el * NN + row0]) = pk;  // row0 % 4 == 0
      }
  }
}

// -------------------- generic 1024^3 bf16 compose: D[m][n] = sum_k X[m][k]*W[n][k] ----
#define BM 128
#define BN 128
#define BK 32
#define LDK 40

__device__ __forceinline__ void compose_body(
    const unsigned short* __restrict__ Xb, const unsigned short* __restrict__ Wb,
    unsigned short* __restrict__ Op, const float* __restrict__ sig, int b, bool tstore) {
  __shared__ unsigned short As[BM * LDK];
  __shared__ unsigned short Bs[BN * LDK];
  const int tid = threadIdx.x;
  const int lane = tid & 63, wave = tid >> 6;
  const int bm = b & 7, bn = b >> 3;
  const int m0 = bm * BM, n0 = bn * BN;
  const int wm = wave & 1, wn = wave >> 1;

  const int srow = tid >> 1;
  const int scol = (tid & 1) << 4;
  const unsigned short* aptr = Xb + (size_t)(m0 + srow) * NN + scol;
  const unsigned short* bptr = Wb + (size_t)(n0 + srow) * NN + scol;

  f32x4 acc[4][4];
#pragma unroll
  for (int a = 0; a < 4; ++a)
#pragma unroll
    for (int bb = 0; bb < 4; ++bb) acc[a][bb] = 0.f;

  uint4 ra0 = *reinterpret_cast<const uint4*>(aptr + 0);
  uint4 ra1 = *reinterpret_cast<const uint4*>(aptr + 8);
  uint4 rb0 = *reinterpret_cast<const uint4*>(bptr + 0);
  uint4 rb1 = *reinterpret_cast<const uint4*>(bptr + 8);

  const int arow0 = wm * 64;
  const int brow0 = wn * 64;
  const int fr = lane & 15;
  const int kb = (lane >> 4) << 3;

#pragma unroll 1
  for (int kt = 0; kt < NN / BK; ++kt) {
    __syncthreads();
    *reinterpret_cast<uint4*>(&As[srow * LDK + scol]) = ra0;
    *reinterpret_cast<uint4*>(&As[srow * LDK + scol + 8]) = ra1;
    *reinterpret_cast<uint4*>(&Bs[srow * LDK + scol]) = rb0;
    *reinterpret_cast<uint4*>(&Bs[srow * LDK + scol + 8]) = rb1;
    __syncthreads();
    if (kt + 1 < NN / BK) {
      const unsigned short* ap = aptr + (kt + 1) * BK;
      const unsigned short* bp = bptr + (kt + 1) * BK;
      ra0 = *reinterpret_cast<const uint4*>(ap + 0);
      ra1 = *reinterpret_cast<const uint4*>(ap + 8);
      rb0 = *reinterpret_cast<const uint4*>(bp + 0);
      rb1 = *reinterpret_cast<const uint4*>(bp + 8);
    }
    short8 af[4], bf[4];
#pragma unroll
    for (int tr = 0; tr < 4; ++tr)
      af[tr] = *reinterpret_cast<const short8*>(&As[(arow0 + tr * 16 + fr) * LDK + kb]);
#pragma unroll
    for (int tc = 0; tc < 4; ++tc)
      bf[tc] = *reinterpret_cast<const short8*>(&Bs[(brow0 + tc * 16 + fr) * LDK + kb]);
#pragma unroll
    for (int tr = 0; tr < 4; ++tr)
#pragma unroll
      for (int tc = 0; tc < 4; ++tc)
        acc[tr][tc] = __builtin_amdgcn_mfma_f32_16x16x32_bf16(af[tr], bf[tc], acc[tr][tc], 0, 0, 0);
  }

  const int rq = (lane >> 4) << 2;
  if (!tstore) {
#pragma unroll
    for (int tc = 0; tc < 4; ++tc) {
      const int gc = n0 + brow0 + tc * 16 + fr;
      const float s = sig ? sig[gc] : 1.0f;
#pragma unroll
      for (int tr = 0; tr < 4; ++tr) {
        const int gr = m0 + arow0 + tr * 16 + rq;
#pragma unroll
        for (int q = 0; q < 4; ++q) {
          Op[(size_t)(gr + q) * NN + gc] = f32_to_bf16_rne(acc[tr][tc][q] * s);
        }
      }
    }
  } else {
#pragma unroll
    for (int tc = 0; tc < 4; ++tc) {
      const int gc = n0 + brow0 + tc * 16 + fr;
#pragma unroll
      for (int tr = 0; tr < 4; ++tr) {
        const int gr = m0 + arow0 + tr * 16 + rq;
        ushort4 pk;
        pk.x = f32_to_bf16_rne(acc[tr][tc][0]);
        pk.y = f32_to_bf16_rne(acc[tr][tc][1]);
        pk.z = f32_to_bf16_rne(acc[tr][tc][2]);
        pk.w = f32_to_bf16_rne(acc[tr][tc][3]);
        *reinterpret_cast<ushort4*>(&Op[(size_t)gc * NN + gr]) = pk;  // gr % 4 == 0
      }
    }
  }
}

#define ME ((size_t)NN * NN)

// L1: 8 pair-products, 512 blocks. U: P_i = ch[2i]*ch[2i+1]; V: P_{4+i} = ch[8+2i]*ch[8+2i+1].
__global__ __launch_bounds__(256) void composeL1_kernel(
    const unsigned short* __restrict__ ch, unsigned short* __restrict__ P) {
  const int sub = blockIdx.x >> 6, b = blockIdx.x & 63;
  const int i = sub & 3;
  const unsigned short* x = ch + (size_t)((sub < 4 ? 0 : 8) + 2 * i) * ME;
  compose_body(x, x + ME, P + (size_t)sub * ME, nullptr, b, (i & 1) != 0);
}

// L2: 4 products, 256 blocks. Q0=P0*P1, Q1=(P2*P3)^T, Q2=P4*P5, Q3=(P6*P7)^T.
__global__ __launch_bounds__(256) void composeL2_kernel(
    const unsigned short* __restrict__ P, unsigned short* __restrict__ Q) {
  const int sub = blockIdx.x >> 6, b = blockIdx.x & 63;
  compose_body(P + (size_t)(2 * sub) * ME, P + (size_t)(2 * sub + 1) * ME,
               Q + (size_t)sub * ME, nullptr, b, (sub & 1) != 0);
}

// L3: MUsig = (Q0*Q1)*sigma (rm), MVt = (Q2*Q3)^T. 128 blocks.
__global__ __launch_bounds__(256) void composeL3_kernel(
    const unsigned short* __restrict__ Q, const float* __restrict__ sigmas,
    unsigned short* __restrict__ F) {
  const int sub = blockIdx.x >> 6, b = blockIdx.x & 63;
  if (sub == 0) compose_body(Q, Q + ME, F, sigmas, b, false);
  else compose_body(Q + 2 * ME, Q + 3 * ME, F + ME, nullptr, b, true);
}

// L4: Mt[n][k] = sum_j MVt[n][j] * MUsig[k][j]. 64 blocks.
__global__ __launch_bounds__(256) void composeL4_kernel(
    const unsigned short* __restrict__ F, unsigned short* __restrict__ Mt) {
  compose_body(F + ME, F, Mt, nullptr, blockIdx.x, false);
}

// -------------------- GEMM: out = x @ M + bias (X f32 -> bf16 on the fly) ----
__global__ __launch_bounds__(256) void gemm_kernel(
    const float* __restrict__ X, const unsigned short* __restrict__ Mt,
    const float* __restrict__ bias, float* __restrict__ Out) {
  __shared__ unsigned short As[BM * LDK];
  __shared__ unsigned short Bs[BN * LDK];
  const int tid = threadIdx.x;
  const int lane = tid & 63, wave = tid >> 6;
  const int bm = blockIdx.x & 127;
  const int bn = blockIdx.x >> 7;
  const int m0 = bm * BM, n0 = bn * BN;
  const int wm = wave & 1, wn = wave >> 1;

  const int srow = tid >> 1;
  const int scol = (tid & 1) << 4;
  const float* aptr = X + (size_t)(m0 + srow) * NN + scol;
  const unsigned short* bptr = Mt + (size_t)(n0 + srow) * NN + scol;

  f32x4 acc[4][4];
#pragma unroll
  for (int a = 0; a < 4; ++a)
#pragma unroll
    for (int b = 0; b < 4; ++b) acc[a][b] = 0.f;

  float4 ra0 = *reinterpret_cast<const float4*>(aptr + 0);
  float4 ra1 = *reinterpret_cast<const float4*>(aptr + 4);
  float4 ra2 = *reinterpret_cast<const float4*>(aptr + 8);
  float4 ra3 = *reinterpret_cast<const float4*>(aptr + 12);
  uint4 rb0 = *reinterpret_cast<const uint4*>(bptr + 0);
  uint4 rb1 = *reinterpret_cast<const uint4*>(bptr + 8);

  const int arow0 = wm * 64;
  const int brow0 = wn * 64;
  const int fr = lane & 15;
  const int kb = (lane >> 4) << 3;

#pragma unroll 1
  for (int kt = 0; kt < NN / BK; ++kt) {
    __syncthreads();
    uint4 w0, w1;
    w0.x = pack2bf(ra0.x, ra0.y); w0.y = pack2bf(ra0.z, ra0.w);
    w0.z = pack2bf(ra1.x, ra1.y); w0.w = pack2bf(ra1.z, ra1.w);
    w1.x = pack2bf(ra2.x, ra2.y); w1.y = pack2bf(ra2.z, ra2.w);
    w1.z = pack2bf(ra3.x, ra3.y); w1.w = pack2bf(ra3.z, ra3.w);
    *reinterpret_cast<uint4*>(&As[srow * LDK + scol]) = w0;
    *reinterpret_cast<uint4*>(&As[srow * LDK + scol + 8]) = w1;
    *reinterpret_cast<uint4*>(&Bs[srow * LDK + scol]) = rb0;
    *reinterpret_cast<uint4*>(&Bs[srow * LDK + scol + 8]) = rb1;
    __syncthreads();
    if (kt + 1 < NN / BK) {
      const float* ap = aptr + (kt + 1) * BK;
      const unsigned short* bp = bptr + (kt + 1) * BK;
      ra0 = *reinterpret_cast<const float4*>(ap + 0);
      ra1 = *reinterpret_cast<const float4*>(ap + 4);
      ra2 = *reinterpret_cast<const float4*>(ap + 8);
      ra3 = *reinterpret_cast<const float4*>(ap + 12);
      rb0 = *reinterpret_cast<const uint4*>(bp + 0);
      rb1 = *reinterpret_cast<const uint4*>(bp + 8);
    }
    short8 af[4], bf[4];
#pragma unroll
    for (int tr = 0; tr < 4; ++tr)
      af[tr] = *reinterpret_cast<const short8*>(&As[(arow0 + tr * 16 + fr) * LDK + kb]);
#pragma unroll
    for (int tc = 0; tc < 4; ++tc)
      bf[tc] = *reinterpret_cast<const short8*>(&Bs[(brow0 + tc * 16 + fr) * LDK + kb]);
#pragma unroll
    for (int tr = 0; tr < 4; ++tr)
#pragma unroll
      for (int tc = 0; tc < 4; ++tc)
        acc[tr][tc] = __builtin_amdgcn_mfma_f32_16x16x32_bf16(af[tr], bf[tc], acc[tr][tc], 0, 0, 0);
  }

  const int rq = (lane >> 4) << 2;
#pragma unroll
  for (int tc = 0; tc < 4; ++tc) {
    const int gc = n0 + brow0 + tc * 16 + fr;
    const float bv = bias[gc];
#pragma unroll
    for (int tr = 0; tr < 4; ++tr) {
      const int gr = m0 + arow0 + tr * 16 + rq;
#pragma unroll
      for (int q = 0; q < 4; ++q) {
        Out[(size_t)(gr + q) * NN + gc] = acc[tr][tc][q] + bv;
      }
    }
  }
}

extern "C" void kernel_launch(void* const* d_in, const int* in_sizes, int n_in,
                              void* d_out, int out_size, void* d_ws, size_t ws_size,
                              hipStream_t stream) {
  const float* x = (const float*)d_in[0];
  const float* U = (const float*)d_in[1];
  const float* V = (const float*)d_in[2];
  const float* p = (const float*)d_in[3];
  const float* bias = (const float*)d_in[4];
  float* out = (float*)d_out;

  char* ws = (char*)d_ws;
  float* tau_u = (float*)(ws);
  float* tau_v = (float*)(ws + 4096);
  float* sigmas = (float*)(ws + 8192);
  float* T8all = (float*)(ws + 16384);                 // 64 KB
  unsigned short* Mt = (unsigned short*)(ws + 81920);  // 2 MB (survives until gemm)

  // 30 x 2MB bf16 temporaries in d_out (64+ MB); all consumed before gemm writes.
  unsigned short* sc = (unsigned short*)d_out;
  unsigned short* chains = sc;             // 16 x ME
  unsigned short* P = sc + 16 * ME;        // 8 x ME
  unsigned short* Q = sc + 24 * ME;        // 4 x ME
  unsigned short* F = sc + 28 * ME;        // 2 x ME (MUsig, MVt)

  prep_kernel<<<516, 256, 0, stream>>>(U, V, p, tau_u, tau_v, sigmas);
  gram_t8_kernel<<<256, 64, 0, stream>>>(U, V, tau_u, tau_v, T8all);
  build16_kernel<<<1024, 256, 0, stream>>>(U, V, T8all, chains);
  composeL1_kernel<<<512, 256, 0, stream>>>(chains, P);
  composeL2_kernel<<<256, 256, 0, stream>>>(P, Q);
  composeL3_kernel<<<128, 256, 0, stream>>>(Q, sigmas, F);
  composeL4_kernel<<<64, 256, 0, stream>>>(F, Mt);
  gemm_kernel<<<1024, 256, 0, stream>>>(x, Mt, bias, out);
}

// Round 11
// 360.393 us; speedup vs baseline: 1.1633x; 1.1633x over previous
//
#include <hip/hip_runtime.h>
#include <stdint.h>

typedef __attribute__((ext_vector_type(8))) short short8;
typedef __attribute__((ext_vector_type(4))) float f32x4;

#define NN 1024
#define NBATCH 16384
#define ME ((size_t)NN * NN)

__device__ __forceinline__ unsigned short f32_to_bf16_rne(float f) {
  unsigned int u = __float_as_uint(f);
  unsigned int r = (u + 0x7fffu + ((u >> 16) & 1u)) >> 16;
  return (unsigned short)r;
}

__device__ __forceinline__ unsigned int pack2bf(float lo, float hi) {
  return (unsigned int)f32_to_bf16_rne(lo) | ((unsigned int)f32_to_bf16_rne(hi) << 16);
}

// split f32 -> bf16 hi + bf16 lo (x ~= hi + lo, captures ~16 mantissa bits)
__device__ __forceinline__ void split_bf16(float x, unsigned short& h, unsigned short& l) {
  h = f32_to_bf16_rne(x);
  float hf = __uint_as_float((unsigned int)h << 16);
  l = f32_to_bf16_rne(x - hf);
}

// 64-lane all-reduce sum (VALU only).
__device__ __forceinline__ float allsum64(float x) {
  x += __int_as_float(__builtin_amdgcn_update_dpp(0, __float_as_int(x), 0xB1, 0xF, 0xF, true));
  x += __int_as_float(__builtin_amdgcn_update_dpp(0, __float_as_int(x), 0x4E, 0xF, 0xF, true));
  x += __int_as_float(__builtin_amdgcn_update_dpp(0, __float_as_int(x), 0x141, 0xF, 0xF, true));
  x += __int_as_float(__builtin_amdgcn_update_dpp(0, __float_as_int(x), 0x140, 0xF, 0xF, true));
#if __has_builtin(__builtin_amdgcn_permlane16_swap) && __has_builtin(__builtin_amdgcn_permlane32_swap)
  {
    auto r16 = __builtin_amdgcn_permlane16_swap(__float_as_uint(x), __float_as_uint(x), false, false);
    x = __uint_as_float(r16[0]) + __uint_as_float(r16[1]);
    auto r32 = __builtin_amdgcn_permlane32_swap(__float_as_uint(x), __float_as_uint(x), false, false);
    x = __uint_as_float(r32[0]) + __uint_as_float(r32[1]);
  }
#else
  x += __int_as_float(__builtin_amdgcn_ds_swizzle(__float_as_int(x), 0x401F));
  x += __shfl_xor(x, 32);
#endif
  return x;
}

// -------------------- prep: tau = 2/(u.u), sigmas --------------------
__global__ __launch_bounds__(256) void prep_kernel(
    const float* __restrict__ U, const float* __restrict__ V,
    const float* __restrict__ p, float* __restrict__ tau_u,
    float* __restrict__ tau_v, float* __restrict__ sigmas) {
  int wave = threadIdx.x >> 6, lane = threadIdx.x & 63;
  int row = blockIdx.x * 4 + wave;
  if (row < 2048) {
    const float* u = (row < NN) ? (U + (size_t)row * NN) : (V + (size_t)(row - NN) * NN);
    float s = 0.f;
#pragma unroll
    for (int t = 0; t < 16; ++t) { float a = u[lane + (t << 6)]; s += a * a; }
    s = allsum64(s);
    if (lane == 0) {
      float tau = 2.0f / s;
      if (row < NN) tau_u[row] = tau;
      else tau_v[row - NN] = tau;
    }
  } else if (row < 2064) {
    int j = ((row - 2048) << 6) + lane;
    float pj = p[j];
    float sg = 1.0f / (1.0f + expf(-pj));
    sigmas[j] = 0.9f * (sg - 0.5f) + 0.55f;  // r=0.45, mean=0.55
  }
}

// -------------------- gram + T8 per block of 8 reflectors --------------------
// blk<128: U bank, rows 8*blk+j (application order j asc). blk>=128: s=blk-128,
// V bank, rows 1023-8s-j (descending application). T8all[blk][r*8+j] = T[r][j].
__global__ __launch_bounds__(64) void gram_t8_kernel(
    const float* __restrict__ U, const float* __restrict__ V,
    const float* __restrict__ tau_u, const float* __restrict__ tau_v,
    float* __restrict__ T8all) {
  __shared__ float G[64];
  const int blk = blockIdx.x;
  const int lane = threadIdx.x;
  const float* bank;
  int rbase, rsign, st;
  if (blk < 128) { bank = U; rbase = 8 * blk; rsign = 1; st = 8 * blk; }
  else { int s = blk - 128; bank = V; rbase = 1023 - 8 * s; rsign = -1; st = 1016 - 8 * s; }

  if (lane < 28) {
    int j = 1, k = 0, t = lane;
    for (int jj = 1; jj < 8; ++jj) {
      int lo = jj * (jj - 1) / 2, hi = jj * (jj + 1) / 2;
      if (t >= lo && t < hi) { j = jj; k = t - lo; }
    }
    const float* rk = bank + (size_t)(rbase + rsign * k) * NN;
    const float* rj = bank + (size_t)(rbase + rsign * j) * NN;
    float acc = 0.f;
    for (int i = st >> 2; i < 256; ++i) {
      float4 a = *reinterpret_cast<const float4*>(rk + 4 * i);
      float4 b = *reinterpret_cast<const float4*>(rj + 4 * i);
      acc += a.x * b.x + a.y * b.y + a.z * b.z + a.w * b.w;
    }
    G[k * 8 + j] = acc;
  }
  __syncthreads();

  if (lane < 8) {
    float Tr[8];
#pragma unroll
    for (int j = 0; j < 8; ++j) Tr[j] = 0.f;
#pragma unroll
    for (int j = 0; j < 8; ++j) {
      int grow = rbase + rsign * j;
      float tj = (blk < 128) ? tau_u[grow] : tau_v[grow];
      float a = 0.f;
#pragma unroll
      for (int k = 0; k < 8; ++k) {
        if (k < j) a += Tr[k] * G[k * 8 + j];
      }
      Tr[j] = (lane == j) ? tj : (-tj * a);
    }
#pragma unroll
    for (int j = 0; j < 8; ++j) T8all[(size_t)blk * 64 + lane * 8 + j] = Tr[j];
  }
}

// -------------------- splitY: chain-slot rows -> split bf16, rm + transposed ----
// Chains: c<8: slot s = U row 128c+s. c>=8: cc=c-8, slot s = V row 1023-128cc-s.
// Outputs: Yhi/Ylo [16*128][1024] row-major; YThi/YTlo [16*1024][128] (Y^T).
__global__ __launch_bounds__(256) void splity_kernel(
    const float* __restrict__ U, const float* __restrict__ V,
    unsigned short* __restrict__ Yhi, unsigned short* __restrict__ Ylo,
    unsigned short* __restrict__ YThi, unsigned short* __restrict__ YTlo) {
  __shared__ float ys[128][129];
  const int tid = threadIdx.x;
  const int c = blockIdx.x >> 3, et = blockIdx.x & 7;
  const int half = tid & 1;
  const int slot = tid >> 1;
  const int e0 = et << 7;
  const int grow = (c < 8) ? ((c << 7) + slot) : (1023 - ((c - 8) << 7) - slot);
  const float* src = ((c < 8) ? U : V) + (size_t)grow * NN + e0 + (half << 6);
#pragma unroll
  for (int i = 0; i < 16; ++i) {
    float4 v4 = *reinterpret_cast<const float4*>(src + (i << 2));
    const int kk = (half << 6) + (i << 2);
    ys[slot][kk + 0] = v4.x; ys[slot][kk + 1] = v4.y;
    ys[slot][kk + 2] = v4.z; ys[slot][kk + 3] = v4.w;
  }
  __syncthreads();
  // row-major split
  {
    const size_t rbase = ((size_t)(c * 128 + slot)) * NN + e0 + (half << 6);
#pragma unroll
    for (int i = 0; i < 16; ++i) {
      const int kk = (half << 6) + (i << 2);
      ushort4 h4, l4;
      split_bf16(ys[slot][kk + 0], h4.x, l4.x);
      split_bf16(ys[slot][kk + 1], h4.y, l4.y);
      split_bf16(ys[slot][kk + 2], h4.z, l4.z);
      split_bf16(ys[slot][kk + 3], h4.w, l4.w);
      *reinterpret_cast<ushort4*>(&Yhi[rbase + (i << 2)]) = h4;
      *reinterpret_cast<ushort4*>(&Ylo[rbase + (i << 2)]) = l4;
    }
  }
  // transposed split: thread owns elem e = slot, k-range = half*64..+63
  {
    const int e = slot;
    const size_t tbase = ((size_t)c * 1024 + e0 + e) * 128 + (half << 6);
#pragma unroll
    for (int i = 0; i < 16; ++i) {
      const int k0 = (half << 6) + (i << 2);
      ushort4 h4, l4;
      split_bf16(ys[k0 + 0][e], h4.x, l4.x);
      split_bf16(ys[k0 + 1][e], h4.y, l4.y);
      split_bf16(ys[k0 + 2][e], h4.z, l4.z);
      split_bf16(ys[k0 + 3][e], h4.w, l4.w);
      *reinterpret_cast<ushort4*>(&YThi[tbase + (i << 2)]) = h4;
      *reinterpret_cast<ushort4*>(&YTlo[tbase + (i << 2)]) = l4;
    }
  }
}

#define LDK 40

// -------------------- gramT: G[c][m][n] = y_m . y_n via split-bf16 MFMA ----
__global__ __launch_bounds__(256) void gramt_kernel(
    const unsigned short* __restrict__ Yhi, const unsigned short* __restrict__ Ylo,
    float* __restrict__ G) {
  __shared__ unsigned short Hs[128 * LDK];
  __shared__ unsigned short Ls[128 * LDK];
  const int tid = threadIdx.x;
  const int lane = tid & 63, wave = tid >> 6;
  const int c = blockIdx.x;
  const int wm = wave & 1, wn = wave >> 1;
  const int srow = tid >> 1, scol = (tid & 1) << 4;
  const unsigned short* ph = Yhi + ((size_t)(c * 128 + srow)) * NN + scol;
  const unsigned short* pl = Ylo + ((size_t)(c * 128 + srow)) * NN + scol;

  f32x4 acc[4][4];
#pragma unroll
  for (int a = 0; a < 4; ++a)
#pragma unroll
    for (int b = 0; b < 4; ++b) acc[a][b] = 0.f;

  const int arow0 = wm * 64, brow0 = wn * 64;
  const int fr = lane & 15, kb = (lane >> 4) << 3;

#pragma unroll 1
  for (int kt = 0; kt < 32; ++kt) {
    __syncthreads();
    *reinterpret_cast<uint4*>(&Hs[srow * LDK + scol]) = *reinterpret_cast<const uint4*>(ph + kt * 32);
    *reinterpret_cast<uint4*>(&Hs[srow * LDK + scol + 8]) = *reinterpret_cast<const uint4*>(ph + kt * 32 + 8);
    *reinterpret_cast<uint4*>(&Ls[srow * LDK + scol]) = *reinterpret_cast<const uint4*>(pl + kt * 32);
    *reinterpret_cast<uint4*>(&Ls[srow * LDK + scol + 8]) = *reinterpret_cast<const uint4*>(pl + kt * 32 + 8);
    __syncthreads();
    short8 ah[4], al[4], bh[4], bl[4];
#pragma unroll
    for (int tr = 0; tr < 4; ++tr) {
      ah[tr] = *reinterpret_cast<const short8*>(&Hs[(arow0 + tr * 16 + fr) * LDK + kb]);
      al[tr] = *reinterpret_cast<const short8*>(&Ls[(arow0 + tr * 16 + fr) * LDK + kb]);
    }
#pragma unroll
    for (int tc = 0; tc < 4; ++tc) {
      bh[tc] = *reinterpret_cast<const short8*>(&Hs[(brow0 + tc * 16 + fr) * LDK + kb]);
      bl[tc] = *reinterpret_cast<const short8*>(&Ls[(brow0 + tc * 16 + fr) * LDK + kb]);
    }
#pragma unroll
    for (int tr = 0; tr < 4; ++tr)
#pragma unroll
      for (int tc = 0; tc < 4; ++tc) {
        acc[tr][tc] = __builtin_amdgcn_mfma_f32_16x16x32_bf16(ah[tr], bh[tc], acc[tr][tc], 0, 0, 0);
        acc[tr][tc] = __builtin_amdgcn_mfma_f32_16x16x32_bf16(ah[tr], bl[tc], acc[tr][tc], 0, 0, 0);
        acc[tr][tc] = __builtin_amdgcn_mfma_f32_16x16x32_bf16(al[tr], bh[tc], acc[tr][tc], 0, 0, 0);
      }
  }
  const int rq = (lane >> 4) << 2;
#pragma unroll
  for (int tc = 0; tc < 4; ++tc) {
    const int gc = brow0 + tc * 16 + fr;
#pragma unroll
    for (int tr = 0; tr < 4; ++tr) {
      const int gr = arow0 + tr * 16 + rq;
#pragma unroll
      for (int q = 0; q < 4; ++q)
        G[((size_t)c * 128 + gr + q) * 128 + gc] = acc[tr][tc][q];
    }
  }
}

// -------------------- ttree: aggregate T8 -> T128 per chain (f32, in LDS) ----
// Merge (Q1 then Q2): T12 = -T1 * G12 * T2, G12[a][b] = y_a.y_b (a left, b right).
__global__ __launch_bounds__(256) void ttree_kernel(
    const float* __restrict__ G, const float* __restrict__ T8all,
    unsigned short* __restrict__ Thi, unsigned short* __restrict__ Tlo) {
  __shared__ float Ts[128 * 128];  // 64 KB
  __shared__ float Gb[64 * 64];    // 16 KB
  __shared__ float Xb[64 * 64];    // 16 KB
  const int c = blockIdx.x, tid = threadIdx.x;
  for (int i = tid; i < 128 * 128; i += 256) Ts[i] = 0.f;
  __syncthreads();
  // diagonal T8 blocks
  for (int i = tid; i < 1024; i += 256) {
    const int sb = i >> 6, ij = i & 63, r = ij >> 3, col = ij & 7;
    const int t8i = (c < 8) ? (16 * c + sb) : (128 + 16 * (c - 8) + sb);
    Ts[(8 * sb + r) * 128 + 8 * sb + col] = T8all[(size_t)t8i * 64 + ij];
  }
  __syncthreads();
  for (int b = 8; b <= 64; b <<= 1) {
    const int nm = 128 / (2 * b);
    for (int m = 0; m < nm; ++m) {
      const int a0 = 2 * b * m;
      for (int i = tid; i < b * b; i += 256) {
        const int r = i / b, cl = i % b;
        Gb[i] = G[((size_t)c * 128 + a0 + r) * 128 + a0 + b + cl];
      }
      __syncthreads();
      // X = G12 * T2 (T2 upper-tri)
      for (int i = tid; i < b * b; i += 256) {
        const int r = i / b, cl = i % b;
        float s = 0.f;
        for (int k = 0; k <= cl; ++k)
          s += Gb[r * b + k] * Ts[(a0 + b + k) * 128 + a0 + b + cl];
        Xb[i] = s;
      }
      __syncthreads();
      // T12 = -T1 * X (T1 upper-tri)
      for (int i = tid; i < b * b; i += 256) {
        const int r = i / b, cl = i % b;
        float s = 0.f;
        for (int k = r; k < b; ++k)
          s -= Ts[(a0 + r) * 128 + a0 + k] * Xb[k * b + cl];
        Ts[(a0 + r) * 128 + a0 + b + cl] = s;
      }
      __syncthreads();
    }
  }
  for (int i = tid; i < 128 * 128; i += 256) {
    unsigned short h, l;
    split_bf16(Ts[i], h, l);
    Thi[(size_t)c * 128 * 128 + i] = h;
    Tlo[(size_t)c * 128 * 128 + i] = l;
  }
}

// -------------------- zw: W = T*Y -> store W^T split bf16. K=128 MFMA ----
// D[a][j] = sum_k T[a][k] * YT[j][k]; store WT[j][a] (hi/lo).
__global__ __launch_bounds__(256) void zw_kernel(
    const unsigned short* __restrict__ Thi, const unsigned short* __restrict__ Tlo,
    const unsigned short* __restrict__ YThi, const unsigned short* __restrict__ YTlo,
    unsigned short* __restrict__ WThi, unsigned short* __restrict__ WTlo) {
  __shared__ unsigned short Xh[128 * LDK], Xl[128 * LDK];
  __shared__ unsigned short Wh[128 * LDK], Wl[128 * LDK];
  const int tid = threadIdx.x;
  const int lane = tid & 63, wave = tid >> 6;
  const int c = blockIdx.x >> 3, bn = blockIdx.x & 7;
  const int n0 = bn * 128;
  const int wm = wave & 1, wn = wave >> 1;
  const int srow = tid >> 1, scol = (tid & 1) << 4;
  const unsigned short* pxh = Thi + ((size_t)c * 128 + srow) * 128 + scol;
  const unsigned short* pxl = Tlo + ((size_t)c * 128 + srow) * 128 + scol;
  const unsigned short* pwh = YThi + ((size_t)c * 1024 + n0 + srow) * 128 + scol;
  const unsigned short* pwl = YTlo + ((size_t)c * 1024 + n0 + srow) * 128 + scol;

  f32x4 acc[4][4];
#pragma unroll
  for (int a = 0; a < 4; ++a)
#pragma unroll
    for (int b = 0; b < 4; ++b) acc[a][b] = 0.f;

  const int arow0 = wm * 64, brow0 = wn * 64;
  const int fr = lane & 15, kb = (lane >> 4) << 3;

#pragma unroll 1
  for (int kt = 0; kt < 4; ++kt) {
    __syncthreads();
    *reinterpret_cast<uint4*>(&Xh[srow * LDK + scol]) = *reinterpret_cast<const uint4*>(pxh + kt * 32);
    *reinterpret_cast<uint4*>(&Xh[srow * LDK + scol + 8]) = *reinterpret_cast<const uint4*>(pxh + kt * 32 + 8);
    *reinterpret_cast<uint4*>(&Xl[srow * LDK + scol]) = *reinterpret_cast<const uint4*>(pxl + kt * 32);
    *reinterpret_cast<uint4*>(&Xl[srow * LDK + scol + 8]) = *reinterpret_cast<const uint4*>(pxl + kt * 32 + 8);
    *reinterpret_cast<uint4*>(&Wh[srow * LDK + scol]) = *reinterpret_cast<const uint4*>(pwh + kt * 32);
    *reinterpret_cast<uint4*>(&Wh[srow * LDK + scol + 8]) = *reinterpret_cast<const uint4*>(pwh + kt * 32 + 8);
    *reinterpret_cast<uint4*>(&Wl[srow * LDK + scol]) = *reinterpret_cast<const uint4*>(pwl + kt * 32);
    *reinterpret_cast<uint4*>(&Wl[srow * LDK + scol + 8]) = *reinterpret_cast<const uint4*>(pwl + kt * 32 + 8);
    __syncthreads();
    short8 ah[4], al[4], bh[4], bl[4];
#pragma unroll
    for (int tr = 0; tr < 4; ++tr) {
      ah[tr] = *reinterpret_cast<const short8*>(&Xh[(arow0 + tr * 16 + fr) * LDK + kb]);
      al[tr] = *reinterpret_cast<const short8*>(&Xl[(arow0 + tr * 16 + fr) * LDK + kb]);
    }
#pragma unroll
    for (int tc = 0; tc < 4; ++tc) {
      bh[tc] = *reinterpret_cast<const short8*>(&Wh[(brow0 + tc * 16 + fr) * LDK + kb]);
      bl[tc] = *reinterpret_cast<const short8*>(&Wl[(brow0 + tc * 16 + fr) * LDK + kb]);
    }
#pragma unroll
    for (int tr = 0; tr < 4; ++tr)
#pragma unroll
      for (int tc = 0; tc < 4; ++tc) {
        acc[tr][tc] = __builtin_amdgcn_mfma_f32_16x16x32_bf16(ah[tr], bh[tc], acc[tr][tc], 0, 0, 0);
        acc[tr][tc] = __builtin_amdgcn_mfma_f32_16x16x32_bf16(ah[tr], bl[tc], acc[tr][tc], 0, 0, 0);
        acc[tr][tc] = __builtin_amdgcn_mfma_f32_16x16x32_bf16(al[tr], bh[tc], acc[tr][tc], 0, 0, 0);
      }
  }
  const int rq = (lane >> 4) << 2;
#pragma unroll
  for (int tc = 0; tc < 4; ++tc) {
    const int gc = brow0 + tc * 16 + fr;
#pragma unroll
    for (int tr = 0; tr < 4; ++tr) {
      const int gr = arow0 + tr * 16 + rq;
      ushort4 h4, l4;
      split_bf16(acc[tr][tc][0], h4.x, l4.x);
      split_bf16(acc[tr][tc][1], h4.y, l4.y);
      split_bf16(acc[tr][tc][2], h4.z, l4.z);
      split_bf16(acc[tr][tc][3], h4.w, l4.w);
      const size_t off = ((size_t)c * 1024 + n0 + gc) * 128 + gr;
      *reinterpret_cast<ushort4*>(&WThi[off]) = h4;
      *reinterpret_cast<ushort4*>(&WTlo[off]) = l4;
    }
  }
}

// -------------------- chainC: C = I - Y^T W per chain. K=128 MFMA ----
// D[m][n] = sum_k YT[m][k]*WT[n][k]; chain = I - D. Even c row-major, odd transposed.
__global__ __launch_bounds__(256) void chainc_kernel(
    const unsigned short* __restrict__ YThi, const unsigned short* __restrict__ YTlo,
    const unsigned short* __restrict__ WThi, const unsigned short* __restrict__ WTlo,
    unsigned short* __restrict__ chains) {
  __shared__ unsigned short Xh[128 * LDK], Xl[128 * LDK];
  __shared__ unsigned short Wh[128 * LDK], Wl[128 * LDK];
  const int tid = threadIdx.x;
  const int lane = tid & 63, wave = tid >> 6;
  const int c = blockIdx.x >> 6, b6 = blockIdx.x & 63;
  const int bm = b6 & 7, bn = b6 >> 3;
  const int m0 = bm * 128, n0 = bn * 128;
  const int wm = wave & 1, wn = wave >> 1;
  const int srow = tid >> 1, scol = (tid & 1) << 4;
  const unsigned short* pxh = YThi + ((size_t)c * 1024 + m0 + srow) * 128 + scol;
  const unsigned short* pxl = YTlo + ((size_t)c * 1024 + m0 + srow) * 128 + scol;
  const unsigned short* pwh = WThi + ((size_t)c * 1024 + n0 + srow) * 128 + scol;
  const unsigned short* pwl = WTlo + ((size_t)c * 1024 + n0 + srow) * 128 + scol;

  f32x4 acc[4][4];
#pragma unroll
  for (int a = 0; a < 4; ++a)
#pragma unroll
    for (int b = 0; b < 4; ++b) acc[a][b] = 0.f;

  const int arow0 = wm * 64, brow0 = wn * 64;
  const int fr = lane & 15, kb = (lane >> 4) << 3;

#pragma unroll 1
  for (int kt = 0; kt < 4; ++kt) {
    __syncthreads();
    *reinterpret_cast<uint4*>(&Xh[srow * LDK + scol]) = *reinterpret_cast<const uint4*>(pxh + kt * 32);
    *reinterpret_cast<uint4*>(&Xh[srow * LDK + scol + 8]) = *reinterpret_cast<const uint4*>(pxh + kt * 32 + 8);
    *reinterpret_cast<uint4*>(&Xl[srow * LDK + scol]) = *reinterpret_cast<const uint4*>(pxl + kt * 32);
    *reinterpret_cast<uint4*>(&Xl[srow * LDK + scol + 8]) = *reinterpret_cast<const uint4*>(pxl + kt * 32 + 8);
    *reinterpret_cast<uint4*>(&Wh[srow * LDK + scol]) = *reinterpret_cast<const uint4*>(pwh + kt * 32);
    *reinterpret_cast<uint4*>(&Wh[srow * LDK + scol + 8]) = *reinterpret_cast<const uint4*>(pwh + kt * 32 + 8);
    *reinterpret_cast<uint4*>(&Wl[srow * LDK + scol]) = *reinterpret_cast<const uint4*>(pwl + kt * 32);
    *reinterpret_cast<uint4*>(&Wl[srow * LDK + scol + 8]) = *reinterpret_cast<const uint4*>(pwl + kt * 32 + 8);
    __syncthreads();
    short8 ah[4], al[4], bh[4], bl[4];
#pragma unroll
    for (int tr = 0; tr < 4; ++tr) {
      ah[tr] = *reinterpret_cast<const short8*>(&Xh[(arow0 + tr * 16 + fr) * LDK + kb]);
      al[tr] = *reinterpret_cast<const short8*>(&Xl[(arow0 + tr * 16 + fr) * LDK + kb]);
    }
#pragma unroll
    for (int tc = 0; tc < 4; ++tc) {
      bh[tc] = *reinterpret_cast<const short8*>(&Wh[(brow0 + tc * 16 + fr) * LDK + kb]);
      bl[tc] = *reinterpret_cast<const short8*>(&Wl[(brow0 + tc * 16 + fr) * LDK + kb]);
    }
#pragma unroll
    for (int tr = 0; tr < 4; ++tr)
#pragma unroll
      for (int tc = 0; tc < 4; ++tc) {
        acc[tr][tc] = __builtin_amdgcn_mfma_f32_16x16x32_bf16(ah[tr], bh[tc], acc[tr][tc], 0, 0, 0);
        acc[tr][tc] = __builtin_amdgcn_mfma_f32_16x16x32_bf16(ah[tr], bl[tc], acc[tr][tc], 0, 0, 0);
        acc[tr][tc] = __builtin_amdgcn_mfma_f32_16x16x32_bf16(al[tr], bh[tc], acc[tr][tc], 0, 0, 0);
      }
  }
  unsigned short* dst = chains + (size_t)c * ME;
  const int rq = (lane >> 4) << 2;
  if ((c & 1) == 0) {
#pragma unroll
    for (int tc = 0; tc < 4; ++tc) {
      const int gcg = n0 + brow0 + tc * 16 + fr;
#pragma unroll
      for (int tr = 0; tr < 4; ++tr) {
        const int grg = m0 + arow0 + tr * 16 + rq;
#pragma unroll
        for (int q = 0; q < 4; ++q) {
          const float val = ((grg + q) == gcg ? 1.0f : 0.0f) - acc[tr][tc][q];
          dst[(size_t)(grg + q) * NN + gcg] = f32_to_bf16_rne(val);
        }
      }
    }
  } else {
#pragma unroll
    for (int tc = 0; tc < 4; ++tc) {
      const int gcg = n0 + brow0 + tc * 16 + fr;
#pragma unroll
      for (int tr = 0; tr < 4; ++tr) {
        const int grg = m0 + arow0 + tr * 16 + rq;
        ushort4 pk;
        pk.x = f32_to_bf16_rne(((grg + 0) == gcg ? 1.0f : 0.0f) - acc[tr][tc][0]);
        pk.y = f32_to_bf16_rne(((grg + 1) == gcg ? 1.0f : 0.0f) - acc[tr][tc][1]);
        pk.z = f32_to_bf16_rne(((grg + 2) == gcg ? 1.0f : 0.0f) - acc[tr][tc][2]);
        pk.w = f32_to_bf16_rne(((grg + 3) == gcg ? 1.0f : 0.0f) - acc[tr][tc][3]);
        *reinterpret_cast<ushort4*>(&dst[(size_t)gcg * NN + grg]) = pk;
      }
    }
  }
}

// -------------------- generic 1024^3 bf16 compose: D[m][n] = sum_k X[m][k]*W[n][k] ----
#define BM 128
#define BN 128
#define BK 32

__device__ __forceinline__ void compose_body(
    const unsigned short* __restrict__ Xb, const unsigned short* __restrict__ Wb,
    unsigned short* __restrict__ Op, const float* __restrict__ sig, int b, bool tstore) {
  __shared__ unsigned short As[BM * LDK];
  __shared__ unsigned short Bs[BN * LDK];
  const int tid = threadIdx.x;
  const int lane = tid & 63, wave = tid >> 6;
  const int bm = b & 7, bn = b >> 3;
  const int m0 = bm * BM, n0 = bn * BN;
  const int wm = wave & 1, wn = wave >> 1;

  const int srow = tid >> 1;
  const int scol = (tid & 1) << 4;
  const unsigned short* aptr = Xb + (size_t)(m0 + srow) * NN + scol;
  const unsigned short* bptr = Wb + (size_t)(n0 + srow) * NN + scol;

  f32x4 acc[4][4];
#pragma unroll
  for (int a = 0; a < 4; ++a)
#pragma unroll
    for (int bb = 0; bb < 4; ++bb) acc[a][bb] = 0.f;

  uint4 ra0 = *reinterpret_cast<const uint4*>(aptr + 0);
  uint4 ra1 = *reinterpret_cast<const uint4*>(aptr + 8);
  uint4 rb0 = *reinterpret_cast<const uint4*>(bptr + 0);
  uint4 rb1 = *reinterpret_cast<const uint4*>(bptr + 8);

  const int arow0 = wm * 64;
  const int brow0 = wn * 64;
  const int fr = lane & 15;
  const int kb = (lane >> 4) << 3;

#pragma unroll 1
  for (int kt = 0; kt < NN / BK; ++kt) {
    __syncthreads();
    *reinterpret_cast<uint4*>(&As[srow * LDK + scol]) = ra0;
    *reinterpret_cast<uint4*>(&As[srow * LDK + scol + 8]) = ra1;
    *reinterpret_cast<uint4*>(&Bs[srow * LDK + scol]) = rb0;
    *reinterpret_cast<uint4*>(&Bs[srow * LDK + scol + 8]) = rb1;
    __syncthreads();
    if (kt + 1 < NN / BK) {
      const unsigned short* ap = aptr + (kt + 1) * BK;
      const unsigned short* bp = bptr + (kt + 1) * BK;
      ra0 = *reinterpret_cast<const uint4*>(ap + 0);
      ra1 = *reinterpret_cast<const uint4*>(ap + 8);
      rb0 = *reinterpret_cast<const uint4*>(bp + 0);
      rb1 = *reinterpret_cast<const uint4*>(bp + 8);
    }
    short8 af[4], bf[4];
#pragma unroll
    for (int tr = 0; tr < 4; ++tr)
      af[tr] = *reinterpret_cast<const short8*>(&As[(arow0 + tr * 16 + fr) * LDK + kb]);
#pragma unroll
    for (int tc = 0; tc < 4; ++tc)
      bf[tc] = *reinterpret_cast<const short8*>(&Bs[(brow0 + tc * 16 + fr) * LDK + kb]);
#pragma unroll
    for (int tr = 0; tr < 4; ++tr)
#pragma unroll
      for (int tc = 0; tc < 4; ++tc)
        acc[tr][tc] = __builtin_amdgcn_mfma_f32_16x16x32_bf16(af[tr], bf[tc], acc[tr][tc], 0, 0, 0);
  }

  const int rq = (lane >> 4) << 2;
  if (!tstore) {
#pragma unroll
    for (int tc = 0; tc < 4; ++tc) {
      const int gc = n0 + brow0 + tc * 16 + fr;
      const float s = sig ? sig[gc] : 1.0f;
#pragma unroll
      for (int tr = 0; tr < 4; ++tr) {
        const int gr = m0 + arow0 + tr * 16 + rq;
#pragma unroll
        for (int q = 0; q < 4; ++q) {
          Op[(size_t)(gr + q) * NN + gc] = f32_to_bf16_rne(acc[tr][tc][q] * s);
        }
      }
    }
  } else {
#pragma unroll
    for (int tc = 0; tc < 4; ++tc) {
      const int gc = n0 + brow0 + tc * 16 + fr;
#pragma unroll
      for (int tr = 0; tr < 4; ++tr) {
        const int gr = m0 + arow0 + tr * 16 + rq;
        ushort4 pk;
        pk.x = f32_to_bf16_rne(acc[tr][tc][0]);
        pk.y = f32_to_bf16_rne(acc[tr][tc][1]);
        pk.z = f32_to_bf16_rne(acc[tr][tc][2]);
        pk.w = f32_to_bf16_rne(acc[tr][tc][3]);
        *reinterpret_cast<ushort4*>(&Op[(size_t)gc * NN + gr]) = pk;  // gr % 4 == 0
      }
    }
  }
}

// L1: 8 pair-products, 512 blocks.
__global__ __launch_bounds__(256) void composeL1_kernel(
    const unsigned short* __restrict__ ch, unsigned short* __restrict__ P) {
  const int sub = blockIdx.x >> 6, b = blockIdx.x & 63;
  const int i = sub & 3;
  const unsigned short* x = ch + (size_t)((sub < 4 ? 0 : 8) + 2 * i) * ME;
  compose_body(x, x + ME, P + (size_t)sub * ME, nullptr, b, (i & 1) != 0);
}

// L2: 4 products, 256 blocks.
__global__ __launch_bounds__(256) void composeL2_kernel(
    const unsigned short* __restrict__ P, unsigned short* __restrict__ Q) {
  const int sub = blockIdx.x >> 6, b = blockIdx.x & 63;
  compose_body(P + (size_t)(2 * sub) * ME, P + (size_t)(2 * sub + 1) * ME,
               Q + (size_t)sub * ME, nullptr, b, (sub & 1) != 0);
}

// L3: MUsig = (Q0*Q1)*sigma (rm), MVt = (Q2*Q3)^T. 128 blocks.
__global__ __launch_bounds__(256) void composeL3_kernel(
    const unsigned short* __restrict__ Q, const float* __restrict__ sigmas,
    unsigned short* __restrict__ F) {
  const int sub = blockIdx.x >> 6, b = blockIdx.x & 63;
  if (sub == 0) compose_body(Q, Q + ME, F, sigmas, b, false);
  else compose_body(Q + 2 * ME, Q + 3 * ME, F + ME, nullptr, b, true);
}

// L4: Mt[n][k] = sum_j MVt[n][j] * MUsig[k][j]. 64 blocks.
__global__ __launch_bounds__(256) void composeL4_kernel(
    const unsigned short* __restrict__ F, unsigned short* __restrict__ Mt) {
  compose_body(F + ME, F, Mt, nullptr, blockIdx.x, false);
}

// -------------------- GEMM: out = x @ M + bias (X f32 -> bf16 on the fly) ----
__global__ __launch_bounds__(256) void gemm_kernel(
    const float* __restrict__ X, const unsigned short* __restrict__ Mt,
    const float* __restrict__ bias, float* __restrict__ Out) {
  __shared__ unsigned short As[BM * LDK];
  __shared__ unsigned short Bs[BN * LDK];
  const int tid = threadIdx.x;
  const int lane = tid & 63, wave = tid >> 6;
  const int bm = blockIdx.x & 127;
  const int bn = blockIdx.x >> 7;
  const int m0 = bm * BM, n0 = bn * BN;
  const int wm = wave & 1, wn = wave >> 1;

  const int srow = tid >> 1;
  const int scol = (tid & 1) << 4;
  const float* aptr = X + (size_t)(m0 + srow) * NN + scol;
  const unsigned short* bptr = Mt + (size_t)(n0 + srow) * NN + scol;

  f32x4 acc[4][4];
#pragma unroll
  for (int a = 0; a < 4; ++a)
#pragma unroll
    for (int b = 0; b < 4; ++b) acc[a][b] = 0.f;

  float4 ra0 = *reinterpret_cast<const float4*>(aptr + 0);
  float4 ra1 = *reinterpret_cast<const float4*>(aptr + 4);
  float4 ra2 = *reinterpret_cast<const float4*>(aptr + 8);
  float4 ra3 = *reinterpret_cast<const float4*>(aptr + 12);
  uint4 rb0 = *reinterpret_cast<const uint4*>(bptr + 0);
  uint4 rb1 = *reinterpret_cast<const uint4*>(bptr + 8);

  const int arow0 = wm * 64;
  const int brow0 = wn * 64;
  const int fr = lane & 15;
  const int kb = (lane >> 4) << 3;

#pragma unroll 1
  for (int kt = 0; kt < NN / BK; ++kt) {
    __syncthreads();
    uint4 w0, w1;
    w0.x = pack2bf(ra0.x, ra0.y); w0.y = pack2bf(ra0.z, ra0.w);
    w0.z = pack2bf(ra1.x, ra1.y); w0.w = pack2bf(ra1.z, ra1.w);
    w1.x = pack2bf(ra2.x, ra2.y); w1.y = pack2bf(ra2.z, ra2.w);
    w1.z = pack2bf(ra3.x, ra3.y); w1.w = pack2bf(ra3.z, ra3.w);
    *reinterpret_cast<uint4*>(&As[srow * LDK + scol]) = w0;
    *reinterpret_cast<uint4*>(&As[srow * LDK + scol + 8]) = w1;
    *reinterpret_cast<uint4*>(&Bs[srow * LDK + scol]) = rb0;
    *reinterpret_cast<uint4*>(&Bs[srow * LDK + scol + 8]) = rb1;
    __syncthreads();
    if (kt + 1 < NN / BK) {
      const float* ap = aptr + (kt + 1) * BK;
      const unsigned short* bp = bptr + (kt + 1) * BK;
      ra0 = *reinterpret_cast<const float4*>(ap + 0);
      ra1 = *reinterpret_cast<const float4*>(ap + 4);
      ra2 = *reinterpret_cast<const float4*>(ap + 8);
      ra3 = *reinterpret_cast<const float4*>(ap + 12);
      rb0 = *reinterpret_cast<const uint4*>(bp + 0);
      rb1 = *reinterpret_cast<const uint4*>(bp + 8);
    }
    short8 af[4], bf[4];
#pragma unroll
    for (int tr = 0; tr < 4; ++tr)
      af[tr] = *reinterpret_cast<const short8*>(&As[(arow0 + tr * 16 + fr) * LDK + kb]);
#pragma unroll
    for (int tc = 0; tc < 4; ++tc)
      bf[tc] = *reinterpret_cast<const short8*>(&Bs[(brow0 + tc * 16 + fr) * LDK + kb]);
#pragma unroll
    for (int tr = 0; tr < 4; ++tr)
#pragma unroll
      for (int tc = 0; tc < 4; ++tc)
        acc[tr][tc] = __builtin_amdgcn_mfma_f32_16x16x32_bf16(af[tr], bf[tc], acc[tr][tc], 0, 0, 0);
  }

  const int rq = (lane >> 4) << 2;
#pragma unroll
  for (int tc = 0; tc < 4; ++tc) {
    const int gc = n0 + brow0 + tc * 16 + fr;
    const float bv = bias[gc];
#pragma unroll
    for (int tr = 0; tr < 4; ++tr) {
      const int gr = m0 + arow0 + tr * 16 + rq;
#pragma unroll
      for (int q = 0; q < 4; ++q) {
        Out[(size_t)(gr + q) * NN + gc] = acc[tr][tc][q] + bv;
      }
    }
  }
}

extern "C" void kernel_launch(void* const* d_in, const int* in_sizes, int n_in,
                              void* d_out, int out_size, void* d_ws, size_t ws_size,
                              hipStream_t stream) {
  const float* x = (const float*)d_in[0];
  const float* U = (const float*)d_in[1];
  const float* V = (const float*)d_in[2];
  const float* p = (const float*)d_in[3];
  const float* bias = (const float*)d_in[4];
  float* out = (float*)d_out;

  char* ws = (char*)d_ws;
  float* tau_u = (float*)(ws);
  float* tau_v = (float*)(ws + 4096);
  float* sigmas = (float*)(ws + 8192);
  float* T8all = (float*)(ws + 16384);                 // 64 KB
  unsigned short* Mt = (unsigned short*)(ws + 81920);  // 2 MB (survives until gemm)

  // d_out (64 MB) scratch layout (ME units of 2 MB), lifetime-overlapped:
  //  [0,16)  chains        (chainC -> L1)
  //  [16,24) YThi/YTlo/WThi/WTlo (splity/zw -> chainC), then P (L1 -> L2)
  //  [24,28) Yhi/Ylo (splity -> gramt), then Q (L2 -> L3)
  //  [28,30) G f32 + Thi/Tlo (gramt/ttree -> zw), then F (L3 -> L4)
  unsigned short* sc = (unsigned short*)d_out;
  unsigned short* chains = sc;
  unsigned short* P = sc + 16 * ME;
  unsigned short* Q = sc + 24 * ME;
  unsigned short* F = sc + 28 * ME;
  unsigned short* YThi = sc + 16 * ME;
  unsigned short* YTlo = sc + 18 * ME;
  unsigned short* WThi = sc + 20 * ME;
  unsigned short* WTlo = sc + 22 * ME;
  unsigned short* Yhi = sc + 24 * ME;
  unsigned short* Ylo = sc + 26 * ME;
  float* G = (float*)(sc + 28 * ME);                   // 1 MB
  unsigned short* Thi = sc + 28 * ME + 524288;         // 0.5 MB
  unsigned short* Tlo = Thi + 262144;                  // 0.5 MB

  prep_kernel<<<516, 256, 0, stream>>>(U, V, p, tau_u, tau_v, sigmas);
  gram_t8_kernel<<<256, 64, 0, stream>>>(U, V, tau_u, tau_v, T8all);
  splity_kernel<<<128, 256, 0, stream>>>(U, V, Yhi, Ylo, YThi, YTlo);
  gramt_kernel<<<16, 256, 0, stream>>>(Yhi, Ylo, G);
  ttree_kernel<<<16, 256, 0, stream>>>(G, T8all, Thi, Tlo);
  zw_kernel<<<128, 256, 0, stream>>>(Thi, Tlo, YThi, YTlo, WThi, WTlo);
  chainc_kernel<<<1024, 256, 0, stream>>>(YThi, YTlo, WThi, WTlo, chains);
  composeL1_kernel<<<512, 256, 0, stream>>>(chains, P);
  composeL2_kernel<<<256, 256, 0, stream>>>(P, Q);
  composeL3_kernel<<<128, 256, 0, stream>>>(Q, sigmas, F);
  composeL4_kernel<<<64, 256, 0, stream>>>(F, Mt);
  gemm_kernel<<<1024, 256, 0, stream>>>(x, Mt, bias, out);
}

// Round 12
// 340.675 us; speedup vs baseline: 1.2306x; 1.0579x over previous
//
#include <hip/hip_runtime.h>
#include <stdint.h>

typedef __attribute__((ext_vector_type(8))) short short8;
typedef __attribute__((ext_vector_type(4))) float f32x4;

#define NN 1024
#define NBATCH 16384
#define ME ((size_t)NN * NN)

__device__ __forceinline__ unsigned short f32_to_bf16_rne(float f) {
  unsigned int u = __float_as_uint(f);
  unsigned int r = (u + 0x7fffu + ((u >> 16) & 1u)) >> 16;
  return (unsigned short)r;
}

__device__ __forceinline__ unsigned int pack2bf(float lo, float hi) {
  return (unsigned int)f32_to_bf16_rne(lo) | ((unsigned int)f32_to_bf16_rne(hi) << 16);
}

// split f32 -> bf16 hi + bf16 lo (x ~= hi + lo, captures ~16 mantissa bits)
__device__ __forceinline__ void split_bf16(float x, unsigned short& h, unsigned short& l) {
  h = f32_to_bf16_rne(x);
  float hf = __uint_as_float((unsigned int)h << 16);
  l = f32_to_bf16_rne(x - hf);
}

// 64-lane all-reduce sum (VALU only).
__device__ __forceinline__ float allsum64(float x) {
  x += __int_as_float(__builtin_amdgcn_update_dpp(0, __float_as_int(x), 0xB1, 0xF, 0xF, true));
  x += __int_as_float(__builtin_amdgcn_update_dpp(0, __float_as_int(x), 0x4E, 0xF, 0xF, true));
  x += __int_as_float(__builtin_amdgcn_update_dpp(0, __float_as_int(x), 0x141, 0xF, 0xF, true));
  x += __int_as_float(__builtin_amdgcn_update_dpp(0, __float_as_int(x), 0x140, 0xF, 0xF, true));
#if __has_builtin(__builtin_amdgcn_permlane16_swap) && __has_builtin(__builtin_amdgcn_permlane32_swap)
  {
    auto r16 = __builtin_amdgcn_permlane16_swap(__float_as_uint(x), __float_as_uint(x), false, false);
    x = __uint_as_float(r16[0]) + __uint_as_float(r16[1]);
    auto r32 = __builtin_amdgcn_permlane32_swap(__float_as_uint(x), __float_as_uint(x), false, false);
    x = __uint_as_float(r32[0]) + __uint_as_float(r32[1]);
  }
#else
  x += __int_as_float(__builtin_amdgcn_ds_swizzle(__float_as_int(x), 0x401F));
  x += __shfl_xor(x, 32);
#endif
  return x;
}

// -------------------- prep: tau = 2/(u.u), sigmas --------------------
__global__ __launch_bounds__(256) void prep_kernel(
    const float* __restrict__ U, const float* __restrict__ V,
    const float* __restrict__ p, float* __restrict__ tau_u,
    float* __restrict__ tau_v, float* __restrict__ sigmas) {
  int wave = threadIdx.x >> 6, lane = threadIdx.x & 63;
  int row = blockIdx.x * 4 + wave;
  if (row < 2048) {
    const float* u = (row < NN) ? (U + (size_t)row * NN) : (V + (size_t)(row - NN) * NN);
    float s = 0.f;
#pragma unroll
    for (int t = 0; t < 16; ++t) { float a = u[lane + (t << 6)]; s += a * a; }
    s = allsum64(s);
    if (lane == 0) {
      float tau = 2.0f / s;
      if (row < NN) tau_u[row] = tau;
      else tau_v[row - NN] = tau;
    }
  } else if (row < 2064) {
    int j = ((row - 2048) << 6) + lane;
    float pj = p[j];
    float sg = 1.0f / (1.0f + expf(-pj));
    sigmas[j] = 0.9f * (sg - 0.5f) + 0.55f;  // r=0.45, mean=0.55
  }
}

// -------------------- gram + T8 per block of 8 reflectors --------------------
__global__ __launch_bounds__(64) void gram_t8_kernel(
    const float* __restrict__ U, const float* __restrict__ V,
    const float* __restrict__ tau_u, const float* __restrict__ tau_v,
    float* __restrict__ T8all) {
  __shared__ float G[64];
  const int blk = blockIdx.x;
  const int lane = threadIdx.x;
  const float* bank;
  int rbase, rsign, st;
  if (blk < 128) { bank = U; rbase = 8 * blk; rsign = 1; st = 8 * blk; }
  else { int s = blk - 128; bank = V; rbase = 1023 - 8 * s; rsign = -1; st = 1016 - 8 * s; }

  if (lane < 28) {
    int j = 1, k = 0, t = lane;
    for (int jj = 1; jj < 8; ++jj) {
      int lo = jj * (jj - 1) / 2, hi = jj * (jj + 1) / 2;
      if (t >= lo && t < hi) { j = jj; k = t - lo; }
    }
    const float* rk = bank + (size_t)(rbase + rsign * k) * NN;
    const float* rj = bank + (size_t)(rbase + rsign * j) * NN;
    float acc = 0.f;
    for (int i = st >> 2; i < 256; ++i) {
      float4 a = *reinterpret_cast<const float4*>(rk + 4 * i);
      float4 b = *reinterpret_cast<const float4*>(rj + 4 * i);
      acc += a.x * b.x + a.y * b.y + a.z * b.z + a.w * b.w;
    }
    G[k * 8 + j] = acc;
  }
  __syncthreads();

  if (lane < 8) {
    float Tr[8];
#pragma unroll
    for (int j = 0; j < 8; ++j) Tr[j] = 0.f;
#pragma unroll
    for (int j = 0; j < 8; ++j) {
      int grow = rbase + rsign * j;
      float tj = (blk < 128) ? tau_u[grow] : tau_v[grow];
      float a = 0.f;
#pragma unroll
      for (int k = 0; k < 8; ++k) {
        if (k < j) a += Tr[k] * G[k * 8 + j];
      }
      Tr[j] = (lane == j) ? tj : (-tj * a);
    }
#pragma unroll
    for (int j = 0; j < 8; ++j) T8all[(size_t)blk * 64 + lane * 8 + j] = Tr[j];
  }
}

// -------------------- splitY: chain-slot rows -> split bf16, rm + transposed ----
__global__ __launch_bounds__(256) void splity_kernel(
    const float* __restrict__ U, const float* __restrict__ V,
    unsigned short* __restrict__ Yhi, unsigned short* __restrict__ Ylo,
    unsigned short* __restrict__ YThi, unsigned short* __restrict__ YTlo) {
  __shared__ float ys[128][129];
  const int tid = threadIdx.x;
  const int c = blockIdx.x >> 3, et = blockIdx.x & 7;
  const int half = tid & 1;
  const int slot = tid >> 1;
  const int e0 = et << 7;
  const int grow = (c < 8) ? ((c << 7) + slot) : (1023 - ((c - 8) << 7) - slot);
  const float* src = ((c < 8) ? U : V) + (size_t)grow * NN + e0 + (half << 6);
#pragma unroll
  for (int i = 0; i < 16; ++i) {
    float4 v4 = *reinterpret_cast<const float4*>(src + (i << 2));
    const int kk = (half << 6) + (i << 2);
    ys[slot][kk + 0] = v4.x; ys[slot][kk + 1] = v4.y;
    ys[slot][kk + 2] = v4.z; ys[slot][kk + 3] = v4.w;
  }
  __syncthreads();
  {
    const size_t rbase = ((size_t)(c * 128 + slot)) * NN + e0 + (half << 6);
#pragma unroll
    for (int i = 0; i < 16; ++i) {
      const int kk = (half << 6) + (i << 2);
      ushort4 h4, l4;
      split_bf16(ys[slot][kk + 0], h4.x, l4.x);
      split_bf16(ys[slot][kk + 1], h4.y, l4.y);
      split_bf16(ys[slot][kk + 2], h4.z, l4.z);
      split_bf16(ys[slot][kk + 3], h4.w, l4.w);
      *reinterpret_cast<ushort4*>(&Yhi[rbase + (i << 2)]) = h4;
      *reinterpret_cast<ushort4*>(&Ylo[rbase + (i << 2)]) = l4;
    }
  }
  {
    const int e = slot;
    const size_t tbase = ((size_t)c * 1024 + e0 + e) * 128 + (half << 6);
#pragma unroll
    for (int i = 0; i < 16; ++i) {
      const int k0 = (half << 6) + (i << 2);
      ushort4 h4, l4;
      split_bf16(ys[k0 + 0][e], h4.x, l4.x);
      split_bf16(ys[k0 + 1][e], h4.y, l4.y);
      split_bf16(ys[k0 + 2][e], h4.z, l4.z);
      split_bf16(ys[k0 + 3][e], h4.w, l4.w);
      *reinterpret_cast<ushort4*>(&YThi[tbase + (i << 2)]) = h4;
      *reinterpret_cast<ushort4*>(&YTlo[tbase + (i << 2)]) = l4;
    }
  }
}

#define LDK 40
#define BM 128
#define BN 128
#define BK 32

// shared fragment+MFMA step (verified layout)
__device__ __forceinline__ void tile_compute(
    const unsigned short* __restrict__ As, const unsigned short* __restrict__ Bs,
    f32x4 acc[4][4], int arow0, int brow0, int fr, int kb) {
  short8 af[4], bf[4];
#pragma unroll
  for (int tr = 0; tr < 4; ++tr)
    af[tr] = *reinterpret_cast<const short8*>(&As[(arow0 + tr * 16 + fr) * LDK + kb]);
#pragma unroll
  for (int tc = 0; tc < 4; ++tc)
    bf[tc] = *reinterpret_cast<const short8*>(&Bs[(brow0 + tc * 16 + fr) * LDK + kb]);
#pragma unroll
  for (int tr = 0; tr < 4; ++tr)
#pragma unroll
    for (int tc = 0; tc < 4; ++tc)
      acc[tr][tc] = __builtin_amdgcn_mfma_f32_16x16x32_bf16(af[tr], bf[tc], acc[tr][tc], 0, 0, 0);
}

// -------------------- gramT (K-split 8x): Gp[c*8+ks] partial grams ----
__global__ __launch_bounds__(256) void gramt_kernel(
    const unsigned short* __restrict__ Yhi, const unsigned short* __restrict__ Ylo,
    float* __restrict__ Gp) {
  __shared__ unsigned short Hs[128 * LDK];
  __shared__ unsigned short Ls[128 * LDK];
  const int tid = threadIdx.x;
  const int lane = tid & 63, wave = tid >> 6;
  const int c = blockIdx.x >> 3, ks = blockIdx.x & 7;
  const int wm = wave & 1, wn = wave >> 1;
  const int srow = tid >> 1, scol = (tid & 1) << 4;
  const unsigned short* ph = Yhi + ((size_t)(c * 128 + srow)) * NN + ks * 128 + scol;
  const unsigned short* pl = Ylo + ((size_t)(c * 128 + srow)) * NN + ks * 128 + scol;

  f32x4 acc[4][4];
#pragma unroll
  for (int a = 0; a < 4; ++a)
#pragma unroll
    for (int b = 0; b < 4; ++b) acc[a][b] = 0.f;

  const int arow0 = wm * 64, brow0 = wn * 64;
  const int fr = lane & 15, kb = (lane >> 4) << 3;

#pragma unroll 1
  for (int kt = 0; kt < 4; ++kt) {
    __syncthreads();
    *reinterpret_cast<uint4*>(&Hs[srow * LDK + scol]) = *reinterpret_cast<const uint4*>(ph + kt * 32);
    *reinterpret_cast<uint4*>(&Hs[srow * LDK + scol + 8]) = *reinterpret_cast<const uint4*>(ph + kt * 32 + 8);
    *reinterpret_cast<uint4*>(&Ls[srow * LDK + scol]) = *reinterpret_cast<const uint4*>(pl + kt * 32);
    *reinterpret_cast<uint4*>(&Ls[srow * LDK + scol + 8]) = *reinterpret_cast<const uint4*>(pl + kt * 32 + 8);
    __syncthreads();
    short8 ah[4], al[4], bh[4], bl[4];
#pragma unroll
    for (int tr = 0; tr < 4; ++tr) {
      ah[tr] = *reinterpret_cast<const short8*>(&Hs[(arow0 + tr * 16 + fr) * LDK + kb]);
      al[tr] = *reinterpret_cast<const short8*>(&Ls[(arow0 + tr * 16 + fr) * LDK + kb]);
    }
#pragma unroll
    for (int tc = 0; tc < 4; ++tc) {
      bh[tc] = *reinterpret_cast<const short8*>(&Hs[(brow0 + tc * 16 + fr) * LDK + kb]);
      bl[tc] = *reinterpret_cast<const short8*>(&Ls[(brow0 + tc * 16 + fr) * LDK + kb]);
    }
#pragma unroll
    for (int tr = 0; tr < 4; ++tr)
#pragma unroll
      for (int tc = 0; tc < 4; ++tc) {
        acc[tr][tc] = __builtin_amdgcn_mfma_f32_16x16x32_bf16(ah[tr], bh[tc], acc[tr][tc], 0, 0, 0);
        acc[tr][tc] = __builtin_amdgcn_mfma_f32_16x16x32_bf16(ah[tr], bl[tc], acc[tr][tc], 0, 0, 0);
        acc[tr][tc] = __builtin_amdgcn_mfma_f32_16x16x32_bf16(al[tr], bh[tc], acc[tr][tc], 0, 0, 0);
      }
  }
  const int rq = (lane >> 4) << 2;
#pragma unroll
  for (int tc = 0; tc < 4; ++tc) {
    const int gc = brow0 + tc * 16 + fr;
#pragma unroll
    for (int tr = 0; tr < 4; ++tr) {
      const int gr = arow0 + tr * 16 + rq;
#pragma unroll
      for (int q = 0; q < 4; ++q)
        Gp[(((size_t)c * 8 + ks) * 128 + gr + q) * 128 + gc] = acc[tr][tc][q];
    }
  }
}

// -------------------- ttree: aggregate T8 -> T128 per chain (f32, in LDS) ----
__global__ __launch_bounds__(256) void ttree_kernel(
    const float* __restrict__ Gp, const float* __restrict__ T8all,
    unsigned short* __restrict__ Thi, unsigned short* __restrict__ Tlo) {
  __shared__ float Ts[128 * 128];  // 64 KB
  __shared__ float Gb[64 * 64];    // 16 KB
  __shared__ float Xb[64 * 64];    // 16 KB
  const int c = blockIdx.x, tid = threadIdx.x;
  for (int i = tid; i < 128 * 128; i += 256) Ts[i] = 0.f;
  __syncthreads();
  for (int i = tid; i < 1024; i += 256) {
    const int sb = i >> 6, ij = i & 63, r = ij >> 3, col = ij & 7;
    const int t8i = (c < 8) ? (16 * c + sb) : (128 + 16 * (c - 8) + sb);
    Ts[(8 * sb + r) * 128 + 8 * sb + col] = T8all[(size_t)t8i * 64 + ij];
  }
  __syncthreads();
  for (int b = 8; b <= 64; b <<= 1) {
    const int nm = 128 / (2 * b);
    for (int m = 0; m < nm; ++m) {
      const int a0 = 2 * b * m;
      for (int i = tid; i < b * b; i += 256) {
        const int r = i / b, cl = i % b;
        float s = 0.f;
#pragma unroll
        for (int sl = 0; sl < 8; ++sl)
          s += Gp[(((size_t)c * 8 + sl) * 128 + a0 + r) * 128 + a0 + b + cl];
        Gb[i] = s;
      }
      __syncthreads();
      for (int i = tid; i < b * b; i += 256) {
        const int r = i / b, cl = i % b;
        float s = 0.f;
        for (int k = 0; k <= cl; ++k)
          s += Gb[r * b + k] * Ts[(a0 + b + k) * 128 + a0 + b + cl];
        Xb[i] = s;
      }
      __syncthreads();
      for (int i = tid; i < b * b; i += 256) {
        const int r = i / b, cl = i % b;
        float s = 0.f;
        for (int k = r; k < b; ++k)
          s -= Ts[(a0 + r) * 128 + a0 + k] * Xb[k * b + cl];
        Ts[(a0 + r) * 128 + a0 + b + cl] = s;
      }
      __syncthreads();
    }
  }
  for (int i = tid; i < 128 * 128; i += 256) {
    unsigned short h, l;
    split_bf16(Ts[i], h, l);
    Thi[(size_t)c * 128 * 128 + i] = h;
    Tlo[(size_t)c * 128 * 128 + i] = l;
  }
}

// -------------------- zw: W = T*Y -> store W^T split bf16 ----
__global__ __launch_bounds__(256) void zw_kernel(
    const unsigned short* __restrict__ Thi, const unsigned short* __restrict__ Tlo,
    const unsigned short* __restrict__ YThi, const unsigned short* __restrict__ YTlo,
    unsigned short* __restrict__ WThi, unsigned short* __restrict__ WTlo) {
  __shared__ unsigned short Xh[128 * LDK], Xl[128 * LDK];
  __shared__ unsigned short Wh[128 * LDK], Wl[128 * LDK];
  const int tid = threadIdx.x;
  const int lane = tid & 63, wave = tid >> 6;
  const int c = blockIdx.x >> 3, bn = blockIdx.x & 7;
  const int n0 = bn * 128;
  const int wm = wave & 1, wn = wave >> 1;
  const int srow = tid >> 1, scol = (tid & 1) << 4;
  const unsigned short* pxh = Thi + ((size_t)c * 128 + srow) * 128 + scol;
  const unsigned short* pxl = Tlo + ((size_t)c * 128 + srow) * 128 + scol;
  const unsigned short* pwh = YThi + ((size_t)c * 1024 + n0 + srow) * 128 + scol;
  const unsigned short* pwl = YTlo + ((size_t)c * 1024 + n0 + srow) * 128 + scol;

  f32x4 acc[4][4];
#pragma unroll
  for (int a = 0; a < 4; ++a)
#pragma unroll
    for (int b = 0; b < 4; ++b) acc[a][b] = 0.f;

  const int arow0 = wm * 64, brow0 = wn * 64;
  const int fr = lane & 15, kb = (lane >> 4) << 3;

#pragma unroll 1
  for (int kt = 0; kt < 4; ++kt) {
    __syncthreads();
    *reinterpret_cast<uint4*>(&Xh[srow * LDK + scol]) = *reinterpret_cast<const uint4*>(pxh + kt * 32);
    *reinterpret_cast<uint4*>(&Xh[srow * LDK + scol + 8]) = *reinterpret_cast<const uint4*>(pxh + kt * 32 + 8);
    *reinterpret_cast<uint4*>(&Xl[srow * LDK + scol]) = *reinterpret_cast<const uint4*>(pxl + kt * 32);
    *reinterpret_cast<uint4*>(&Xl[srow * LDK + scol + 8]) = *reinterpret_cast<const uint4*>(pxl + kt * 32 + 8);
    *reinterpret_cast<uint4*>(&Wh[srow * LDK + scol]) = *reinterpret_cast<const uint4*>(pwh + kt * 32);
    *reinterpret_cast<uint4*>(&Wh[srow * LDK + scol + 8]) = *reinterpret_cast<const uint4*>(pwh + kt * 32 + 8);
    *reinterpret_cast<uint4*>(&Wl[srow * LDK + scol]) = *reinterpret_cast<const uint4*>(pwl + kt * 32);
    *reinterpret_cast<uint4*>(&Wl[srow * LDK + scol + 8]) = *reinterpret_cast<const uint4*>(pwl + kt * 32 + 8);
    __syncthreads();
    short8 ah[4], al[4], bh[4], bl[4];
#pragma unroll
    for (int tr = 0; tr < 4; ++tr) {
      ah[tr] = *reinterpret_cast<const short8*>(&Xh[(arow0 + tr * 16 + fr) * LDK + kb]);
      al[tr] = *reinterpret_cast<const short8*>(&Xl[(arow0 + tr * 16 + fr) * LDK + kb]);
    }
#pragma unroll
    for (int tc = 0; tc < 4; ++tc) {
      bh[tc] = *reinterpret_cast<const short8*>(&Wh[(brow0 + tc * 16 + fr) * LDK + kb]);
      bl[tc] = *reinterpret_cast<const short8*>(&Wl[(brow0 + tc * 16 + fr) * LDK + kb]);
    }
#pragma unroll
    for (int tr = 0; tr < 4; ++tr)
#pragma unroll
      for (int tc = 0; tc < 4; ++tc) {
        acc[tr][tc] = __builtin_amdgcn_mfma_f32_16x16x32_bf16(ah[tr], bh[tc], acc[tr][tc], 0, 0, 0);
        acc[tr][tc] = __builtin_amdgcn_mfma_f32_16x16x32_bf16(ah[tr], bl[tc], acc[tr][tc], 0, 0, 0);
        acc[tr][tc] = __builtin_amdgcn_mfma_f32_16x16x32_bf16(al[tr], bh[tc], acc[tr][tc], 0, 0, 0);
      }
  }
  const int rq = (lane >> 4) << 2;
#pragma unroll
  for (int tc = 0; tc < 4; ++tc) {
    const int gc = brow0 + tc * 16 + fr;
#pragma unroll
    for (int tr = 0; tr < 4; ++tr) {
      const int gr = arow0 + tr * 16 + rq;
      ushort4 h4, l4;
      split_bf16(acc[tr][tc][0], h4.x, l4.x);
      split_bf16(acc[tr][tc][1], h4.y, l4.y);
      split_bf16(acc[tr][tc][2], h4.z, l4.z);
      split_bf16(acc[tr][tc][3], h4.w, l4.w);
      const size_t off = ((size_t)c * 1024 + n0 + gc) * 128 + gr;
      *reinterpret_cast<ushort4*>(&WThi[off]) = h4;
      *reinterpret_cast<ushort4*>(&WTlo[off]) = l4;
    }
  }
}

// -------------------- chainC: C = I - Y^T W per chain ----
__global__ __launch_bounds__(256) void chainc_kernel(
    const unsigned short* __restrict__ YThi, const unsigned short* __restrict__ YTlo,
    const unsigned short* __restrict__ WThi, const unsigned short* __restrict__ WTlo,
    unsigned short* __restrict__ chains) {
  __shared__ unsigned short Xh[128 * LDK], Xl[128 * LDK];
  __shared__ unsigned short Wh[128 * LDK], Wl[128 * LDK];
  const int tid = threadIdx.x;
  const int lane = tid & 63, wave = tid >> 6;
  const int c = blockIdx.x >> 6, b6 = blockIdx.x & 63;
  const int bm = b6 & 7, bn = b6 >> 3;
  const int m0 = bm * 128, n0 = bn * 128;
  const int wm = wave & 1, wn = wave >> 1;
  const int srow = tid >> 1, scol = (tid & 1) << 4;
  const unsigned short* pxh = YThi + ((size_t)c * 1024 + m0 + srow) * 128 + scol;
  const unsigned short* pxl = YTlo + ((size_t)c * 1024 + m0 + srow) * 128 + scol;
  const unsigned short* pwh = WThi + ((size_t)c * 1024 + n0 + srow) * 128 + scol;
  const unsigned short* pwl = WTlo + ((size_t)c * 1024 + n0 + srow) * 128 + scol;

  f32x4 acc[4][4];
#pragma unroll
  for (int a = 0; a < 4; ++a)
#pragma unroll
    for (int b = 0; b < 4; ++b) acc[a][b] = 0.f;

  const int arow0 = wm * 64, brow0 = wn * 64;
  const int fr = lane & 15, kb = (lane >> 4) << 3;

#pragma unroll 1
  for (int kt = 0; kt < 4; ++kt) {
    __syncthreads();
    *reinterpret_cast<uint4*>(&Xh[srow * LDK + scol]) = *reinterpret_cast<const uint4*>(pxh + kt * 32);
    *reinterpret_cast<uint4*>(&Xh[srow * LDK + scol + 8]) = *reinterpret_cast<const uint4*>(pxh + kt * 32 + 8);
    *reinterpret_cast<uint4*>(&Xl[srow * LDK + scol]) = *reinterpret_cast<const uint4*>(pxl + kt * 32);
    *reinterpret_cast<uint4*>(&Xl[srow * LDK + scol + 8]) = *reinterpret_cast<const uint4*>(pxl + kt * 32 + 8);
    *reinterpret_cast<uint4*>(&Wh[srow * LDK + scol]) = *reinterpret_cast<const uint4*>(pwh + kt * 32);
    *reinterpret_cast<uint4*>(&Wh[srow * LDK + scol + 8]) = *reinterpret_cast<const uint4*>(pwh + kt * 32 + 8);
    *reinterpret_cast<uint4*>(&Wl[srow * LDK + scol]) = *reinterpret_cast<const uint4*>(pwl + kt * 32);
    *reinterpret_cast<uint4*>(&Wl[srow * LDK + scol + 8]) = *reinterpret_cast<const uint4*>(pwl + kt * 32 + 8);
    __syncthreads();
    short8 ah[4], al[4], bh[4], bl[4];
#pragma unroll
    for (int tr = 0; tr < 4; ++tr) {
      ah[tr] = *reinterpret_cast<const short8*>(&Xh[(arow0 + tr * 16 + fr) * LDK + kb]);
      al[tr] = *reinterpret_cast<const short8*>(&Xl[(arow0 + tr * 16 + fr) * LDK + kb]);
    }
#pragma unroll
    for (int tc = 0; tc < 4; ++tc) {
      bh[tc] = *reinterpret_cast<const short8*>(&Wh[(brow0 + tc * 16 + fr) * LDK + kb]);
      bl[tc] = *reinterpret_cast<const short8*>(&Wl[(brow0 + tc * 16 + fr) * LDK + kb]);
    }
#pragma unroll
    for (int tr = 0; tr < 4; ++tr)
#pragma unroll
      for (int tc = 0; tc < 4; ++tc) {
        acc[tr][tc] = __builtin_amdgcn_mfma_f32_16x16x32_bf16(ah[tr], bh[tc], acc[tr][tc], 0, 0, 0);
        acc[tr][tc] = __builtin_amdgcn_mfma_f32_16x16x32_bf16(ah[tr], bl[tc], acc[tr][tc], 0, 0, 0);
        acc[tr][tc] = __builtin_amdgcn_mfma_f32_16x16x32_bf16(al[tr], bh[tc], acc[tr][tc], 0, 0, 0);
      }
  }
  unsigned short* dst = chains + (size_t)c * ME;
  const int rq = (lane >> 4) << 2;
  if ((c & 1) == 0) {
#pragma unroll
    for (int tc = 0; tc < 4; ++tc) {
      const int gcg = n0 + brow0 + tc * 16 + fr;
#pragma unroll
      for (int tr = 0; tr < 4; ++tr) {
        const int grg = m0 + arow0 + tr * 16 + rq;
#pragma unroll
        for (int q = 0; q < 4; ++q) {
          const float val = ((grg + q) == gcg ? 1.0f : 0.0f) - acc[tr][tc][q];
          dst[(size_t)(grg + q) * NN + gcg] = f32_to_bf16_rne(val);
        }
      }
    }
  } else {
#pragma unroll
    for (int tc = 0; tc < 4; ++tc) {
      const int gcg = n0 + brow0 + tc * 16 + fr;
#pragma unroll
      for (int tr = 0; tr < 4; ++tr) {
        const int grg = m0 + arow0 + tr * 16 + rq;
        ushort4 pk;
        pk.x = f32_to_bf16_rne(((grg + 0) == gcg ? 1.0f : 0.0f) - acc[tr][tc][0]);
        pk.y = f32_to_bf16_rne(((grg + 1) == gcg ? 1.0f : 0.0f) - acc[tr][tc][1]);
        pk.z = f32_to_bf16_rne(((grg + 2) == gcg ? 1.0f : 0.0f) - acc[tr][tc][2]);
        pk.w = f32_to_bf16_rne(((grg + 3) == gcg ? 1.0f : 0.0f) - acc[tr][tc][3]);
        *reinterpret_cast<ushort4*>(&dst[(size_t)gcg * NN + grg]) = pk;
      }
    }
  }
}

// -------------------- 1024^3 bf16 compose, pipelined ----
// Double-buffered LDS + 2-deep register prefetch + raw s_barrier w/ manual
// lgkmcnt(0) (loads stay in flight across barriers; __syncthreads would drain
// vmcnt(0) -> the R11 95us gemm stall). One barrier per k-step.
__device__ __forceinline__ void compose_body(
    const unsigned short* __restrict__ Xb, const unsigned short* __restrict__ Wb,
    unsigned short* __restrict__ Op, const float* __restrict__ sig, int b, bool tstore) {
  __shared__ unsigned short As[2][BM * LDK];
  __shared__ unsigned short Bs[2][BN * LDK];
  const int tid = threadIdx.x;
  const int lane = tid & 63, wave = tid >> 6;
  const int bm = b & 7, bn = b >> 3;
  const int m0 = bm * BM, n0 = bn * BN;
  const int wm = wave & 1, wn = wave >> 1;

  const int srow = tid >> 1;
  const int scol = (tid & 1) << 4;
  const unsigned short* aptr = Xb + (size_t)(m0 + srow) * NN + scol;
  const unsigned short* bptr = Wb + (size_t)(n0 + srow) * NN + scol;

  f32x4 acc[4][4];
#pragma unroll
  for (int a = 0; a < 4; ++a)
#pragma unroll
    for (int bb = 0; bb < 4; ++bb) acc[a][bb] = 0.f;

  // two register sets: even k-steps (E) and odd k-steps (O)
  uint4 raE0 = *reinterpret_cast<const uint4*>(aptr + 0);
  uint4 raE1 = *reinterpret_cast<const uint4*>(aptr + 8);
  uint4 rbE0 = *reinterpret_cast<const uint4*>(bptr + 0);
  uint4 rbE1 = *reinterpret_cast<const uint4*>(bptr + 8);
  uint4 raO0 = *reinterpret_cast<const uint4*>(aptr + BK);
  uint4 raO1 = *reinterpret_cast<const uint4*>(aptr + BK + 8);
  uint4 rbO0 = *reinterpret_cast<const uint4*>(bptr + BK);
  uint4 rbO1 = *reinterpret_cast<const uint4*>(bptr + BK + 8);

  const int arow0 = wm * 64;
  const int brow0 = wn * 64;
  const int fr = lane & 15;
  const int kb = (lane >> 4) << 3;

#define CB_STEP(PB, RA0, RA1, RB0, RB1, KT)                                    \
  {                                                                            \
    *reinterpret_cast<uint4*>(&As[PB][srow * LDK + scol]) = RA0;               \
    *reinterpret_cast<uint4*>(&As[PB][srow * LDK + scol + 8]) = RA1;           \
    *reinterpret_cast<uint4*>(&Bs[PB][srow * LDK + scol]) = RB0;               \
    *reinterpret_cast<uint4*>(&Bs[PB][srow * LDK + scol + 8]) = RB1;           \
    if ((KT) + 2 < 32) {                                                       \
      RA0 = *reinterpret_cast<const uint4*>(aptr + ((KT) + 2) * BK);           \
      RA1 = *reinterpret_cast<const uint4*>(aptr + ((KT) + 2) * BK + 8);       \
      RB0 = *reinterpret_cast<const uint4*>(bptr + ((KT) + 2) * BK);           \
      RB1 = *reinterpret_cast<const uint4*>(bptr + ((KT) + 2) * BK + 8);       \
    }                                                                          \
    asm volatile("s_waitcnt lgkmcnt(0)" ::: "memory");                         \
    __builtin_amdgcn_s_barrier();                                              \
    __builtin_amdgcn_sched_barrier(0);                                         \
    tile_compute(&As[PB][0], &Bs[PB][0], acc, arow0, brow0, fr, kb);           \
  }

#pragma unroll 1
  for (int kt2 = 0; kt2 < 16; ++kt2) {
    CB_STEP(0, raE0, raE1, rbE0, rbE1, 2 * kt2)
    CB_STEP(1, raO0, raO1, rbO0, rbO1, 2 * kt2 + 1)
  }
#undef CB_STEP

  const int rq = (lane >> 4) << 2;
  if (!tstore) {
#pragma unroll
    for (int tc = 0; tc < 4; ++tc) {
      const int gc = n0 + brow0 + tc * 16 + fr;
      const float s = sig ? sig[gc] : 1.0f;
#pragma unroll
      for (int tr = 0; tr < 4; ++tr) {
        const int gr = m0 + arow0 + tr * 16 + rq;
#pragma unroll
        for (int q = 0; q < 4; ++q) {
          Op[(size_t)(gr + q) * NN + gc] = f32_to_bf16_rne(acc[tr][tc][q] * s);
        }
      }
    }
  } else {
#pragma unroll
    for (int tc = 0; tc < 4; ++tc) {
      const int gc = n0 + brow0 + tc * 16 + fr;
#pragma unroll
      for (int tr = 0; tr < 4; ++tr) {
        const int gr = m0 + arow0 + tr * 16 + rq;
        ushort4 pk;
        pk.x = f32_to_bf16_rne(acc[tr][tc][0]);
        pk.y = f32_to_bf16_rne(acc[tr][tc][1]);
        pk.z = f32_to_bf16_rne(acc[tr][tc][2]);
        pk.w = f32_to_bf16_rne(acc[tr][tc][3]);
        *reinterpret_cast<ushort4*>(&Op[(size_t)gc * NN + gr]) = pk;  // gr % 4 == 0
      }
    }
  }
}

// L1: 8 pair-products, 512 blocks.
__global__ __launch_bounds__(256) void composeL1_kernel(
    const unsigned short* __restrict__ ch, unsigned short* __restrict__ P) {
  const int sub = blockIdx.x >> 6, b = blockIdx.x & 63;
  const int i = sub & 3;
  const unsigned short* x = ch + (size_t)((sub < 4 ? 0 : 8) + 2 * i) * ME;
  compose_body(x, x + ME, P + (size_t)sub * ME, nullptr, b, (i & 1) != 0);
}

// L2: 4 products, 256 blocks.
__global__ __launch_bounds__(256) void composeL2_kernel(
    const unsigned short* __restrict__ P, unsigned short* __restrict__ Q) {
  const int sub = blockIdx.x >> 6, b = blockIdx.x & 63;
  compose_body(P + (size_t)(2 * sub) * ME, P + (size_t)(2 * sub + 1) * ME,
               Q + (size_t)sub * ME, nullptr, b, (sub & 1) != 0);
}

// L3: MUsig = (Q0*Q1)*sigma (rm), MVt = (Q2*Q3)^T. 128 blocks.
__global__ __launch_bounds__(256) void composeL3_kernel(
    const unsigned short* __restrict__ Q, const float* __restrict__ sigmas,
    unsigned short* __restrict__ F) {
  const int sub = blockIdx.x >> 6, b = blockIdx.x & 63;
  if (sub == 0) compose_body(Q, Q + ME, F, sigmas, b, false);
  else compose_body(Q + 2 * ME, Q + 3 * ME, F + ME, nullptr, b, true);
}

// L4: Mt[n][k] = sum_j MVt[n][j] * MUsig[k][j]. 64 blocks.
__global__ __launch_bounds__(256) void composeL4_kernel(
    const unsigned short* __restrict__ F, unsigned short* __restrict__ Mt) {
  compose_body(F + ME, F, Mt, nullptr, blockIdx.x, false);
}

// -------------------- GEMM: out = x @ M + bias, pipelined like compose ----
__global__ __launch_bounds__(256) void gemm_kernel(
    const float* __restrict__ X, const unsigned short* __restrict__ Mt,
    const float* __restrict__ bias, float* __restrict__ Out) {
  __shared__ unsigned short As[2][BM * LDK];
  __shared__ unsigned short Bs[2][BN * LDK];
  const int tid = threadIdx.x;
  const int lane = tid & 63, wave = tid >> 6;
  const int bm = blockIdx.x & 127;
  const int bn = blockIdx.x >> 7;
  const int m0 = bm * BM, n0 = bn * BN;
  const int wm = wave & 1, wn = wave >> 1;

  const int srow = tid >> 1;
  const int scol = (tid & 1) << 4;
  const float* aptr = X + (size_t)(m0 + srow) * NN + scol;
  const unsigned short* bptr = Mt + (size_t)(n0 + srow) * NN + scol;

  f32x4 acc[4][4];
#pragma unroll
  for (int a = 0; a < 4; ++a)
#pragma unroll
    for (int b = 0; b < 4; ++b) acc[a][b] = 0.f;

  float4 rE0 = *reinterpret_cast<const float4*>(aptr + 0);
  float4 rE1 = *reinterpret_cast<const float4*>(aptr + 4);
  float4 rE2 = *reinterpret_cast<const float4*>(aptr + 8);
  float4 rE3 = *reinterpret_cast<const float4*>(aptr + 12);
  uint4 bE0 = *reinterpret_cast<const uint4*>(bptr + 0);
  uint4 bE1 = *reinterpret_cast<const uint4*>(bptr + 8);
  float4 rO0 = *reinterpret_cast<const float4*>(aptr + BK);
  float4 rO1 = *reinterpret_cast<const float4*>(aptr + BK + 4);
  float4 rO2 = *reinterpret_cast<const float4*>(aptr + BK + 8);
  float4 rO3 = *reinterpret_cast<const float4*>(aptr + BK + 12);
  uint4 bO0 = *reinterpret_cast<const uint4*>(bptr + BK);
  uint4 bO1 = *reinterpret_cast<const uint4*>(bptr + BK + 8);

  const int arow0 = wm * 64;
  const int brow0 = wn * 64;
  const int fr = lane & 15;
  const int kb = (lane >> 4) << 3;

#define GM_STEP(PB, A0, A1, A2, A3, B0, B1, KT)                                \
  {                                                                            \
    uint4 w0, w1;                                                              \
    w0.x = pack2bf(A0.x, A0.y); w0.y = pack2bf(A0.z, A0.w);                    \
    w0.z = pack2bf(A1.x, A1.y); w0.w = pack2bf(A1.z, A1.w);                    \
    w1.x = pack2bf(A2.x, A2.y); w1.y = pack2bf(A2.z, A2.w);                    \
    w1.z = pack2bf(A3.x, A3.y); w1.w = pack2bf(A3.z, A3.w);                    \
    *reinterpret_cast<uint4*>(&As[PB][srow * LDK + scol]) = w0;                \
    *reinterpret_cast<uint4*>(&As[PB][srow * LDK + scol + 8]) = w1;            \
    *reinterpret_cast<uint4*>(&Bs[PB][srow * LDK + scol]) = B0;                \
    *reinterpret_cast<uint4*>(&Bs[PB][srow * LDK + scol + 8]) = B1;            \
    if ((KT) + 2 < 32) {                                                       \
      const float* ap = aptr + ((KT) + 2) * BK;                                \
      const unsigned short* bp = bptr + ((KT) + 2) * BK;                       \
      A0 = *reinterpret_cast<const float4*>(ap + 0);                           \
      A1 = *reinterpret_cast<const float4*>(ap + 4);                           \
      A2 = *reinterpret_cast<const float4*>(ap + 8);                           \
      A3 = *reinterpret_cast<const float4*>(ap + 12);                          \
      B0 = *reinterpret_cast<const uint4*>(bp + 0);                            \
      B1 = *reinterpret_cast<const uint4*>(bp + 8);                            \
    }                                                                          \
    asm volatile("s_waitcnt lgkmcnt(0)" ::: "memory");                         \
    __builtin_amdgcn_s_barrier();                                              \
    __builtin_amdgcn_sched_barrier(0);                                         \
    tile_compute(&As[PB][0], &Bs[PB][0], acc, arow0, brow0, fr, kb);           \
  }

#pragma unroll 1
  for (int kt2 = 0; kt2 < 16; ++kt2) {
    GM_STEP(0, rE0, rE1, rE2, rE3, bE0, bE1, 2 * kt2)
    GM_STEP(1, rO0, rO1, rO2, rO3, bO0, bO1, 2 * kt2 + 1)
  }
#undef GM_STEP

  const int rq = (lane >> 4) << 2;
#pragma unroll
  for (int tc = 0; tc < 4; ++tc) {
    const int gc = n0 + brow0 + tc * 16 + fr;
    const float bv = bias[gc];
#pragma unroll
    for (int tr = 0; tr < 4; ++tr) {
      const int gr = m0 + arow0 + tr * 16 + rq;
#pragma unroll
      for (int q = 0; q < 4; ++q) {
        Out[(size_t)(gr + q) * NN + gc] = acc[tr][tc][q] + bv;
      }
    }
  }
}

extern "C" void kernel_launch(void* const* d_in, const int* in_sizes, int n_in,
                              void* d_out, int out_size, void* d_ws, size_t ws_size,
                              hipStream_t stream) {
  const float* x = (const float*)d_in[0];
  const float* U = (const float*)d_in[1];
  const float* V = (const float*)d_in[2];
  const float* p = (const float*)d_in[3];
  const float* bias = (const float*)d_in[4];
  float* out = (float*)d_out;

  char* ws = (char*)d_ws;
  float* tau_u = (float*)(ws);
  float* tau_v = (float*)(ws + 4096);
  float* sigmas = (float*)(ws + 8192);
  float* T8all = (float*)(ws + 16384);                 // 64 KB
  unsigned short* Mt = (unsigned short*)(ws + 81920);  // 2 MB (survives until gemm)

  // d_out (64 MB = 32 ME-units) scratch, lifetime-overlapped:
  //  [0,16)  chains (chainC -> L1)
  //  [16,24) YT/WT (splity/zw -> chainc), then P (L1 -> L2)
  //  [24,28) Yhi/Ylo (splity -> gramt), then Thi/Tlo (ttree -> zw), then Q (L2 -> L3)
  //  [28,32) Gp 8MB f32 (gramt -> ttree), then F at [28,30) (L3 -> L4)
  unsigned short* sc = (unsigned short*)d_out;
  unsigned short* chains = sc;
  unsigned short* P = sc + 16 * ME;
  unsigned short* Q = sc + 24 * ME;
  unsigned short* F = sc + 28 * ME;
  unsigned short* YThi = sc + 16 * ME;
  unsigned short* YTlo = sc + 18 * ME;
  unsigned short* WThi = sc + 20 * ME;
  unsigned short* WTlo = sc + 22 * ME;
  unsigned short* Yhi = sc + 24 * ME;
  unsigned short* Ylo = sc + 26 * ME;
  float* Gp = (float*)(sc + 28 * ME);                  // 16*8*128*128*4B = 8 MB
  unsigned short* Thi = sc + 24 * ME;                  // reuses dead Yhi region
  unsigned short* Tlo = Thi + 262144;

  prep_kernel<<<516, 256, 0, stream>>>(U, V, p, tau_u, tau_v, sigmas);
  gram_t8_kernel<<<256, 64, 0, stream>>>(U, V, tau_u, tau_v, T8all);
  splity_kernel<<<128, 256, 0, stream>>>(U, V, Yhi, Ylo, YThi, YTlo);
  gramt_kernel<<<128, 256, 0, stream>>>(Yhi, Ylo, Gp);
  ttree_kernel<<<16, 256, 0, stream>>>(Gp, T8all, Thi, Tlo);
  zw_kernel<<<128, 256, 0, stream>>>(Thi, Tlo, YThi, YTlo, WThi, WTlo);
  chainc_kernel<<<1024, 256, 0, stream>>>(YThi, YTlo, WThi, WTlo, chains);
  composeL1_kernel<<<512, 256, 0, stream>>>(chains, P);
  composeL2_kernel<<<256, 256, 0, stream>>>(P, Q);
  composeL3_kernel<<<128, 256, 0, stream>>>(Q, sigmas, F);
  composeL4_kernel<<<64, 256, 0, stream>>>(F, Mt);
  gemm_kernel<<<1024, 256, 0, stream>>>(x, Mt, bias, out);
}